// Round 14
// baseline (467.592 us; speedup 1.0000x reference)
//
#include <hip/hip_runtime.h>

// GNN_79937931313503: dynamic-graph SAGE GNN on MI355X.
// R14: launch-count cuts (merged prep, deg folded into sim2, inline last-block
// scans) + aggA address strength-reduction (running pointers).

typedef __attribute__((ext_vector_type(8))) short s8v;   // 8 x bf16 (4 VGPR)
typedef __attribute__((ext_vector_type(4))) float f4v;   // MFMA C/D frag

__device__ __forceinline__ f4v MFMA(s8v a, s8v b, f4v c) {
  return __builtin_amdgcn_mfma_f32_16x16x32_bf16(a, b, c, 0, 0, 0);
}
__device__ __forceinline__ short f2bf(float f) {  // RNE float->bf16 bits
  unsigned u = __float_as_uint(f);
  return (short)((u + 0x7FFFu + ((u >> 16) & 1u)) >> 16);
}
__device__ __forceinline__ float bf2f(short s) {
  return __uint_as_float(((unsigned)(unsigned short)s) << 16);
}

#define NT64 128
#define NTRI 8256  // 128*129/2
#define NHC 8      // global histogram copies

__device__ __forceinline__ void tri_invert(int t, int& r, int& c) {
  int rr = (int)((257.0f - sqrtf((float)(257 * 257 - 8 * t))) * 0.5f);
  if (rr < 0) rr = 0;
  if (rr > 127) rr = 127;
  while (rr < 127 && ((rr + 1) * NT64 - (rr + 1) * rr / 2) <= t) ++rr;
  while (rr > 0 && (rr * NT64 - rr * (rr - 1) / 2) > t) --rr;
  r = rr;
  c = rr + (t - (rr * NT64 - rr * (rr - 1) / 2));
}

// A-layout (F): chunk (row>>4, k>>5)*512; elem (m,k) at lane=((k>>3)&3)*16+m, e=k&7
// B-layout (BF): chunk (feat>>4)*256+(node>>5); elem at lane=((node>>3)&3)*16+feat&15

// ---------------- prep: x (blocks 0..127) + weights (blocks 128..1279) ------
__global__ __launch_bounds__(256) void prep_kernel(
    const float* __restrict__ x, const float* __restrict__ w_in,
    const float* __restrict__ w1l, const float* __restrict__ w1r,
    const float* __restrict__ w2l, const float* __restrict__ w2r,
    short* __restrict__ xbF, short* __restrict__ xnF, short* __restrict__ w_inF,
    short* __restrict__ w1lF, short* __restrict__ w1rF,
    short* __restrict__ w2lF, short* __restrict__ w2rF) {
  if (blockIdx.x < 128) {
    const int w = threadIdx.x >> 6, lane = threadIdx.x & 63;
    const int rg = blockIdx.x * 4 + w;
    const int m = lane & 15, g = lane >> 4;
    const int row = rg * 16 + m;
    float v[4][8];
    float ss = 0.f;
#pragma unroll
    for (int kc = 0; kc < 4; ++kc) {
      const float* src = x + row * 128 + kc * 32 + g * 8;
      float4 a = *(const float4*)src;
      float4 b = *(const float4*)(src + 4);
      v[kc][0] = a.x; v[kc][1] = a.y; v[kc][2] = a.z; v[kc][3] = a.w;
      v[kc][4] = b.x; v[kc][5] = b.y; v[kc][6] = b.z; v[kc][7] = b.w;
#pragma unroll
      for (int e = 0; e < 8; ++e) ss += v[kc][e] * v[kc][e];
    }
    ss += __shfl_xor(ss, 16);
    ss += __shfl_xor(ss, 32);
    float inv = 1.0f / fmaxf(sqrtf(ss), 1e-8f);
#pragma unroll
    for (int kc = 0; kc < 4; ++kc) {
      s8v raw, nrm;
#pragma unroll
      for (int e = 0; e < 8; ++e) {
        raw[e] = f2bf(v[kc][e]);
        nrm[e] = f2bf(v[kc][e] * inv);
      }
      *(s8v*)(xbF + (rg * 4 + kc) * 512 + lane * 8) = raw;
      *(s8v*)(xnF + (rg * 4 + kc) * 512 + lane * 8) = nrm;
    }
    return;
  }
  int idx = (blockIdx.x - 128) * 256 + threadIdx.x;
  if (idx >= 294912) return;
  if (idx < 32768) {                       // w_in [128k][256n], K=128
    int n = idx >> 7, k = idx & 127;
    size_t pos = (size_t)((n >> 4) * 4 + (k >> 5)) * 512 +
                 (((k >> 3) & 3) * 16 + (n & 15)) * 8 + (k & 7);
    w_inF[pos] = f2bf(w_in[k * 256 + n]);
  } else {
    int j = idx - 32768;
    int m = j >> 16, r = j & 65535;
    int n = r >> 8, k = r & 255;
    const float* src = (m == 0) ? w1l : (m == 1) ? w1r : (m == 2) ? w2l : w2r;
    short* dst = (m == 0) ? w1lF : (m == 1) ? w1rF : (m == 2) ? w2lF : w2rF;
    size_t pos = (size_t)((n >> 4) * 8 + (k >> 5)) * 512 +
                 (((k >> 3) & 3) * 16 + (n & 15)) * 8 + (k & 7);
    dst[pos] = f2bf(src[k * 256 + n]);
  }
}

// ---------------- hist0: persistent histogram + inline last-block scan ------
__global__ __launch_bounds__(256) void hist0_kernel(const short* __restrict__ xnF,
                                                    unsigned int* __restrict__ hist,
                                                    unsigned int* __restrict__ sel) {
  __shared__ unsigned int lh[4096];
  const int tid = threadIdx.x, w = tid >> 6, lane = tid & 63;
  for (int b = tid; b < 4096; b += 256) lh[b] = 0;
  __syncthreads();

  for (int tg = blockIdx.x; tg < NTRI / 4; tg += gridDim.x) {
    int t = tg * 4 + w;
    int r, c;
    tri_invert(t, r, c);
    const bool diag = (r == c);
    f4v acc[4][4];
#pragma unroll
    for (int a = 0; a < 4; ++a)
#pragma unroll
      for (int b = 0; b < 4; ++b) acc[a][b] = (f4v){0.f, 0.f, 0.f, 0.f};
    const int rga = r * 4, rgb = c * 4;
#pragma unroll
    for (int kc = 0; kc < 4; ++kc) {
      s8v af[4], bf[4];
#pragma unroll
      for (int mt = 0; mt < 4; ++mt)
        af[mt] = *(const s8v*)(xnF + ((rga + mt) * 4 + kc) * 512 + lane * 8);
#pragma unroll
      for (int nt = 0; nt < 4; ++nt)
        bf[nt] = *(const s8v*)(xnF + ((rgb + nt) * 4 + kc) * 512 + lane * 8);
#pragma unroll
      for (int mt = 0; mt < 4; ++mt)
#pragma unroll
        for (int nt = 0; nt < 4; ++nt) acc[mt][nt] = MFMA(af[mt], bf[nt], acc[mt][nt]);
    }
    unsigned wgt = diag ? 1u : 2u;
#pragma unroll
    for (int mt = 0; mt < 4; ++mt)
      for (int nt = 0; nt < 4; ++nt)
        for (int rr = 0; rr < 4; ++rr) {
          float val = fabsf(acc[mt][nt][rr]);
          int bin = (int)(val * 4096.0f);
          bin = min(max(bin, 0), 4095);
          atomicAdd(&lh[bin], wgt);
        }
  }
  __syncthreads();
  unsigned int* hc = hist + (blockIdx.x & (NHC - 1)) * 4096;
  for (int b = tid; b < 4096; b += 256)
    if (lh[b]) atomicAdd(&hc[b], lh[b]);
  // last-block inline scan
  __threadfence();
  __shared__ unsigned lastflag;
  if (tid == 0) lastflag = (atomicAdd(&sel[8], 1u) == gridDim.x - 1) ? 1u : 0u;
  __syncthreads();
  if (!lastflag) return;
  volatile const unsigned* vh = hist;
  unsigned long long* csum = (unsigned long long*)lh;  // reuse LDS
  const int PER = 16;
  unsigned vals[16];
  unsigned long long s = 0;
  for (int i = 0; i < PER; ++i) {
    unsigned v = 0;
    for (int cc = 0; cc < NHC; ++cc) v += vh[cc * 4096 + tid * PER + i];
    vals[i] = v;
    s += v;
  }
  csum[tid] = s;
  __syncthreads();
  for (int o = 1; o < 256; o <<= 1) {
    unsigned long long prev = (tid >= o) ? csum[tid - o] : 0ull;
    __syncthreads();
    csum[tid] += prev;
    __syncthreads();
  }
  unsigned long long K = 63753421ull;
  unsigned long long inc = csum[tid], exc = inc - s;
  if (K > exc && K <= inc) {
    unsigned long long c = exc;
    for (int i = 0; i < PER; ++i) {
      c += vals[i];
      if (c >= K) {
        sel[0] = (unsigned)(tid * PER + i);
        sel[1] = (unsigned)(K - (c - vals[i]));
        break;
      }
    }
  }
}

// ---------------- sim: per-wave 64x64 tiles, upper triangle only ------------
// MODE 1: refine histogram + inline last-block scan -> sel[2]=eps bits.
// MODE 2: adjacency bitmask + AT + degree-count atomics.
template <int MODE>
__global__ __launch_bounds__(256) void sim_kernel(
    const short* __restrict__ xnF, unsigned int* __restrict__ hist,
    unsigned int* __restrict__ sel, unsigned long long* __restrict__ Awords,
    unsigned long long* __restrict__ AT, int* __restrict__ degcnt) {
  const int tid = threadIdx.x, w = tid >> 6, lane = tid & 63;
  int t = blockIdx.x * 4 + w;
  int r, c;
  tri_invert(t, r, c);
  const int i0 = r * 64, j0 = c * 64;
  const bool diag = (r == c);

  f4v acc[4][4];
#pragma unroll
  for (int a = 0; a < 4; ++a)
#pragma unroll
    for (int b = 0; b < 4; ++b) acc[a][b] = (f4v){0.f, 0.f, 0.f, 0.f};

  const int rga = r * 4, rgb = c * 4;
#pragma unroll
  for (int kc = 0; kc < 4; ++kc) {
    s8v af[4], bf[4];
#pragma unroll
    for (int mt = 0; mt < 4; ++mt)
      af[mt] = *(const s8v*)(xnF + ((rga + mt) * 4 + kc) * 512 + lane * 8);
#pragma unroll
    for (int nt = 0; nt < 4; ++nt)
      bf[nt] = *(const s8v*)(xnF + ((rgb + nt) * 4 + kc) * 512 + lane * 8);
#pragma unroll
    for (int mt = 0; mt < 4; ++mt)
#pragma unroll
      for (int nt = 0; nt < 4; ++nt) acc[mt][nt] = MFMA(af[mt], bf[nt], acc[mt][nt]);
  }

  if (MODE == 1) {
    int pref = (int)sel[0];
    unsigned wgt = diag ? 1u : 2u;
#pragma unroll
    for (int mt = 0; mt < 4; ++mt)
      for (int nt = 0; nt < 4; ++nt)
        for (int rr = 0; rr < 4; ++rr) {
          float tt = fabsf(acc[mt][nt][rr]) * 4096.0f;
          int bin = min(max((int)tt, 0), 4095);
          if (bin == pref) {
            int b2 = (int)((tt - (float)pref) * 8192.0f);
            b2 = min(max(b2, 0), 8191);
            atomicAdd(&hist[b2], wgt);
          }
        }
    // last-block inline scan of the 8192-bin refine histogram
    __threadfence();
    __shared__ unsigned lastflag;
    __shared__ unsigned long long csum[256];
    if (tid == 0) lastflag = (atomicAdd(&sel[9], 1u) == gridDim.x - 1) ? 1u : 0u;
    __syncthreads();
    if (!lastflag) return;
    volatile const unsigned* vh = hist;
    const int PER = 32;
    unsigned vals[32];
    unsigned long long s = 0;
    for (int i = 0; i < PER; ++i) {
      vals[i] = vh[tid * PER + i];
      s += vals[i];
    }
    csum[tid] = s;
    __syncthreads();
    for (int o = 1; o < 256; o <<= 1) {
      unsigned long long prev = (tid >= o) ? csum[tid - o] : 0ull;
      __syncthreads();
      csum[tid] += prev;
      __syncthreads();
    }
    unsigned long long K = (unsigned long long)sel[1];
    unsigned long long inc = csum[tid], exc = inc - s;
    if (K > exc && K <= inc) {
      unsigned long long cacc = exc;
      for (int i = 0; i < PER; ++i) {
        cacc += vals[i];
        if (cacc >= K) {
          float eps = ((float)sel[0] + (float)(tid * PER + i) * (1.0f / 8192.0f)) *
                      (1.0f / 4096.0f);
          sel[2] = __float_as_uint(eps);
          break;
        }
      }
    }
  } else {
    float eps = __uint_as_float(sel[2]);
    unsigned long long myword = 0;  // lane j holds row (i0+j)'s bits [j0..j0+64)
#pragma unroll
    for (int mt = 0; mt < 4; ++mt)
#pragma unroll
      for (int rr = 0; rr < 4; ++rr) {
        unsigned long long b0 = __ballot(fabsf(acc[mt][0][rr]) >= eps);
        unsigned long long b1 = __ballot(fabsf(acc[mt][1][rr]) >= eps);
        unsigned long long b2 = __ballot(fabsf(acc[mt][2][rr]) >= eps);
        unsigned long long b3 = __ballot(fabsf(acc[mt][3][rr]) >= eps);
        if ((lane >> 4) == mt && (lane & 3) == rr) {
          int gj = (lane >> 2) & 3;
          myword = ((b0 >> (16 * gj)) & 0xFFFFull) |
                   (((b1 >> (16 * gj)) & 0xFFFFull) << 16) |
                   (((b2 >> (16 * gj)) & 0xFFFFull) << 32) |
                   (((b3 >> (16 * gj)) & 0xFFFFull) << 48);
        }
      }
    Awords[(size_t)(i0 + lane) * 128 + (j0 >> 6)] = myword;
    AT[(size_t)(j0 >> 6) * 8192 + i0 + lane] = myword;
    atomicAdd(&degcnt[i0 + lane], __popcll(myword));
    if (!diag) {  // mirrored tile via 64x64 bit transpose (ballot per column)
      unsigned long long tw = 0;
#pragma unroll
      for (int c2 = 0; c2 < 64; ++c2) {
        unsigned long long bc = __ballot((myword >> c2) & 1ull);
        if (lane == c2) tw = bc;
      }
      Awords[(size_t)(j0 + lane) * 128 + (i0 >> 6)] = tw;
      AT[(size_t)(i0 >> 6) * 8192 + j0 + lane] = tw;
      atomicAdd(&degcnt[j0 + lane], __popcll(tw));
    }
  }
}

// ---------------- lin: F-layout GEMM ----------------------------------------
template <bool TWO, bool RELU, bool RES, bool WF, bool WBF, bool WRM>
__global__ __launch_bounds__(256) void lin_kernel(
    const short* __restrict__ A1, const short* __restrict__ B1, int K1,
    const short* __restrict__ A2, const short* __restrict__ B2, int K2,
    const float* __restrict__ bias, const short* __restrict__ resF,
    short* __restrict__ outF, short* __restrict__ outBF, short* __restrict__ outRM) {
  const int i0 = blockIdx.x * 64, n0 = blockIdx.y * 64;
  const int tid = threadIdx.x, w = tid >> 6, lane = tid & 63;
  const int wy = (w >> 1) * 32, wx = (w & 1) * 32;
  f4v acc[2][2];
#pragma unroll
  for (int a = 0; a < 2; ++a)
#pragma unroll
    for (int b = 0; b < 2; ++b) acc[a][b] = (f4v){0.f, 0.f, 0.f, 0.f};

  const int ka = K1 >> 5;
  const int ra0 = (i0 + wy) >> 4, rb0 = (n0 + wx) >> 4;
  for (int cc = 0; cc < ka; ++cc) {
    s8v a0 = *(const s8v*)(A1 + ((ra0 + 0) * ka + cc) * 512 + lane * 8);
    s8v a1 = *(const s8v*)(A1 + ((ra0 + 1) * ka + cc) * 512 + lane * 8);
    s8v b0 = *(const s8v*)(B1 + ((rb0 + 0) * ka + cc) * 512 + lane * 8);
    s8v b1 = *(const s8v*)(B1 + ((rb0 + 1) * ka + cc) * 512 + lane * 8);
    acc[0][0] = MFMA(a0, b0, acc[0][0]);
    acc[0][1] = MFMA(a0, b1, acc[0][1]);
    acc[1][0] = MFMA(a1, b0, acc[1][0]);
    acc[1][1] = MFMA(a1, b1, acc[1][1]);
  }
  if constexpr (TWO) {
    const int kb = K2 >> 5;
    for (int cc = 0; cc < kb; ++cc) {
      s8v a0 = *(const s8v*)(A2 + ((ra0 + 0) * kb + cc) * 512 + lane * 8);
      s8v a1 = *(const s8v*)(A2 + ((ra0 + 1) * kb + cc) * 512 + lane * 8);
      s8v b0 = *(const s8v*)(B2 + ((rb0 + 0) * kb + cc) * 512 + lane * 8);
      s8v b1 = *(const s8v*)(B2 + ((rb0 + 1) * kb + cc) * 512 + lane * 8);
      acc[0][0] = MFMA(a0, b0, acc[0][0]);
      acc[0][1] = MFMA(a0, b1, acc[0][1]);
      acc[1][0] = MFMA(a1, b0, acc[1][0]);
      acc[1][1] = MFMA(a1, b1, acc[1][1]);
    }
  }
#pragma unroll
  for (int mt = 0; mt < 2; ++mt)
#pragma unroll
    for (int nt = 0; nt < 2; ++nt)
#pragma unroll
      for (int rr = 0; rr < 4; ++rr) {
        int row = i0 + wy + mt * 16 + (lane >> 4) * 4 + rr;
        int col = n0 + wx + nt * 16 + (lane & 15);
        float v = acc[mt][nt][rr] + bias[col];
        if constexpr (RES) {
          v += bf2f(resF[(size_t)((row >> 4) * 8 + (col >> 5)) * 512 +
                         (((col >> 3) & 3) * 16 + (row & 15)) * 8 + (col & 7)]);
        }
        if constexpr (RELU) v = fmaxf(v, 0.f);
        short sv = f2bf(v);
        if constexpr (WRM) outRM[row * 256 + col] = sv;
        if constexpr (WF) {
          outF[(size_t)((row >> 4) * 8 + (col >> 5)) * 512 +
               (((col >> 3) & 3) * 16 + (row & 15)) * 8 + (col & 7)] = sv;
        }
        if constexpr (WBF) {
          outBF[(size_t)((col >> 4) * 256 + (row >> 5)) * 512 +
                (((row >> 3) & 3) * 16 + (col & 15)) * 8 + (row & 7)] = sv;
        }
      }
}

// ---------------- aggA: partialF[z] = Fmajor(A[:, kslice] @ h[kslice, :]) ----
// Running pointers (strength-reduced addressing).
__global__ __launch_bounds__(256, 3) void aggA_kernel(
    const unsigned long long* __restrict__ AT, const short* __restrict__ hBF,
    short* __restrict__ partial, int ksplit) {
  const int i0 = blockIdx.x * 128;
  const int f0 = blockIdx.y * 128;
  const int k0 = blockIdx.z * ksplit;
  const int tid = threadIdx.x, w = tid >> 6, lane = tid & 63;
  const int wy = (w >> 1) * 64, wx = f0 + (w & 1) * 64;
  const int lr = lane & 15, g = lane >> 4, g8 = g * 8;

  f4v acc[4][4];
#pragma unroll
  for (int a = 0; a < 4; ++a)
#pragma unroll
    for (int b = 0; b < 4; ++b) acc[a][b] = (f4v){0.f, 0.f, 0.f, 0.f};

  const unsigned long long* awp = AT + (size_t)(k0 >> 6) * 8192 + i0 + wy + lr;
  const short* bp0 = hBF + ((size_t)(wx >> 4) * 256 + (k0 >> 5)) * 512 + lane * 8;
  const short* bp1 = bp0 + 131072;   // +1 chunk-row of 256*512 shorts
  const short* bp2 = bp0 + 262144;
  const short* bp3 = bp0 + 393216;

  for (int kb = 0; kb < ksplit; kb += 64) {
    unsigned long long aw[4];
#pragma unroll
    for (int mt = 0; mt < 4; ++mt) aw[mt] = awp[mt * 16];
#pragma unroll
    for (int kc = 0; kc < 2; ++kc) {
      s8v bf[4];
      bf[0] = *(const s8v*)(bp0 + kc * 512);
      bf[1] = *(const s8v*)(bp1 + kc * 512);
      bf[2] = *(const s8v*)(bp2 + kc * 512);
      bf[3] = *(const s8v*)(bp3 + kc * 512);
#pragma unroll
      for (int mt = 0; mt < 4; ++mt) {
        unsigned byte = ((unsigned)(aw[mt] >> (kc * 32)) >> g8) & 0xFFu;
        unsigned ad0, ad1, ad2, ad3;
        ad0 = ((byte & 1u) | ((byte & 2u) << 15)) * 0x3F80u;
        ad1 = (((byte >> 2) & 1u) | (((byte >> 2) & 2u) << 15)) * 0x3F80u;
        ad2 = (((byte >> 4) & 1u) | (((byte >> 4) & 2u) << 15)) * 0x3F80u;
        ad3 = (((byte >> 6) & 1u) | (((byte >> 6) & 2u) << 15)) * 0x3F80u;
        unsigned adv[4] = {ad0, ad1, ad2, ad3};
        s8v a;
        __builtin_memcpy(&a, adv, 16);
#pragma unroll
        for (int nt = 0; nt < 4; ++nt) acc[mt][nt] = MFMA(a, bf[nt], acc[mt][nt]);
      }
    }
    awp += 8192;
    bp0 += 1024; bp1 += 1024; bp2 += 1024; bp3 += 1024;
  }
  short* P = partial + (size_t)blockIdx.z * 2097152;
#pragma unroll
  for (int mt = 0; mt < 4; ++mt)
#pragma unroll
    for (int nt = 0; nt < 4; ++nt)
#pragma unroll
      for (int rr = 0; rr < 4; ++rr) {
        int row = i0 + wy + mt * 16 + g * 4 + rr;
        int col = wx + nt * 16 + lr;
        P[(size_t)((row >> 4) * 8 + (col >> 5)) * 512 +
          (((col >> 3) & 3) * 16 + (row & 15)) * 8 + (col & 7)] = f2bf(acc[mt][nt][rr]);
      }
}

// combine: aggF = bf16((sum_z partialF[z]) / deg); A-layout in+out
__global__ __launch_bounds__(256) void combine_kernel(const short* __restrict__ p, int nsplit,
                                                      const int* __restrict__ degcnt,
                                                      short* __restrict__ aggF) {
  int idx8 = blockIdx.x * 256 + threadIdx.x;  // one s8v group in A-layout
  float s[8];
#pragma unroll
  for (int e = 0; e < 8; ++e) s[e] = 0.f;
  for (int k = 0; k < nsplit; ++k) {
    s8v v = *(const s8v*)(p + (size_t)k * 2097152 + (size_t)idx8 * 8);
#pragma unroll
    for (int e = 0; e < 8; ++e) s[e] += bf2f(v[e]);
  }
  int chunk = idx8 >> 6, lane = idx8 & 63;
  int row = (chunk >> 3) * 16 + (lane & 15);
  float di = 1.0f / (float)max(degcnt[row], 1);
  s8v o;
#pragma unroll
  for (int e = 0; e < 8; ++e) o[e] = f2bf(s[e] * di);
  *(s8v*)(aggF + (size_t)idx8 * 8) = o;
}

// ---------------- tail ----------------
__global__ __launch_bounds__(256) void vec3_kernel(const short* __restrict__ h2,
                                                   const float* __restrict__ o1wl,
                                                   const float* __restrict__ o1wr,
                                                   const float* __restrict__ oscw,
                                                   const float* __restrict__ oscb,
                                                   float* __restrict__ u, float* __restrict__ v,
                                                   float* __restrict__ sc) {
  int row = blockIdx.x * 4 + (threadIdx.x >> 6);
  int lane = threadIdx.x & 63;
  float su = 0.f, sv = 0.f, ss = 0.f;
#pragma unroll
  for (int e = 0; e < 4; ++e) {
    int k = lane * 4 + e;
    float hv = bf2f(h2[row * 256 + k]);
    su += hv * o1wl[k];
    sv += hv * o1wr[k];
    ss += hv * oscw[k];
  }
  for (int o = 1; o < 64; o <<= 1) {
    su += __shfl_xor(su, o);
    sv += __shfl_xor(sv, o);
    ss += __shfl_xor(ss, o);
  }
  if (lane == 0) {
    u[row] = su;
    v[row] = sv;
    sc[row] = ss + oscb[0];
  }
}

__global__ __launch_bounds__(256) void aggv1_kernel(const unsigned long long* __restrict__ Awords,
                                                    const float* __restrict__ u,
                                                    const int* __restrict__ degcnt,
                                                    const float* __restrict__ v,
                                                    const float* __restrict__ o1bl,
                                                    float* __restrict__ o1) {
  int row = blockIdx.x * 4 + (threadIdx.x >> 6);
  int lane = threadIdx.x & 63;
  float s = 0.f;
#pragma unroll
  for (int wi = 0; wi < 2; ++wi) {
    unsigned long long bits = Awords[row * 128 + wi * 64 + lane];
    int base = (wi * 64 + lane) * 64;
    while (bits) {
      int b = __ffsll(bits) - 1;
      s += u[base + b];
      bits &= bits - 1;
    }
  }
  for (int o = 1; o < 64; o <<= 1) s += __shfl_xor(s, o);
  if (lane == 0) {
    float di = 1.0f / (float)max(degcnt[row], 1);
    o1[row] = fmaxf(s * di + o1bl[0] + v[row], 0.f);
  }
}

__global__ __launch_bounds__(256) void aggv2_kernel(const unsigned long long* __restrict__ Awords,
                                                    const float* __restrict__ o1,
                                                    const int* __restrict__ degcnt,
                                                    const float* __restrict__ o2wl,
                                                    const float* __restrict__ o2bl,
                                                    const float* __restrict__ o2wr,
                                                    const float* __restrict__ sc,
                                                    float* __restrict__ out) {
  int row = blockIdx.x * 4 + (threadIdx.x >> 6);
  int lane = threadIdx.x & 63;
  float s = 0.f;
#pragma unroll
  for (int wi = 0; wi < 2; ++wi) {
    unsigned long long bits = Awords[row * 128 + wi * 64 + lane];
    int base = (wi * 64 + lane) * 64;
    while (bits) {
      int b = __ffsll(bits) - 1;
      s += o1[base + b];
      bits &= bits - 1;
    }
  }
  for (int o = 1; o < 64; o <<= 1) s += __shfl_xor(s, o);
  if (lane == 0) {
    float di = 1.0f / (float)max(degcnt[row], 1);
    float z = s * di * o2wl[0] + o2bl[0] + o1[row] * o2wr[0] + sc[row];
    out[row] = 1.f / (1.f + expf(-z));
  }
}

// ---------------- launch ----------------
extern "C" void kernel_launch(void* const* d_in, const int* in_sizes, int n_in,
                              void* d_out, int out_size, void* d_ws, size_t ws_size,
                              hipStream_t stream) {
  (void)in_sizes; (void)n_in; (void)out_size;
  const float* x     = (const float*)d_in[0];
  const float* w_in  = (const float*)d_in[1];
  const float* b_in  = (const float*)d_in[2];
  const float* h1_wl = (const float*)d_in[3];
  const float* h1_bl = (const float*)d_in[4];
  const float* h1_wr = (const float*)d_in[5];
  const float* h2_wl = (const float*)d_in[6];
  const float* h2_bl = (const float*)d_in[7];
  const float* h2_wr = (const float*)d_in[8];
  const float* o1_wl = (const float*)d_in[9];
  const float* o1_bl = (const float*)d_in[10];
  const float* o1_wr = (const float*)d_in[11];
  const float* o2_wl = (const float*)d_in[12];
  const float* o2_bl = (const float*)d_in[13];
  const float* o2_wr = (const float*)d_in[14];
  const float* osc_w = (const float*)d_in[15];
  const float* osc_b = (const float*)d_in[16];
  float* out = (float*)d_out;

  char* ws = (char*)d_ws;
  size_t off = 0;
  auto alloc = [&](size_t bytes) -> char* {
    char* p = ws + off;
    off += (bytes + 255) & ~(size_t)255;
    return p;
  };
  short* xnF   = (short*)alloc(8192 * 128 * 2);
  short* xbF   = (short*)alloc(8192 * 128 * 2);
  short* w_inF = (short*)alloc(256 * 128 * 2);
  short* w1lF  = (short*)alloc(256 * 256 * 2);
  short* w1rF  = (short*)alloc(256 * 256 * 2);
  short* w2lF  = (short*)alloc(256 * 256 * 2);
  short* w2rF  = (short*)alloc(256 * 256 * 2);
  // zeroed region: hist1 | hist2 | sel(+counters) | degcnt — contiguous
  unsigned int* hist1 = (unsigned int*)alloc(NHC * 4096 * 4);
  unsigned int* hist2 = (unsigned int*)alloc(8192 * 4);
  unsigned int* sel   = (unsigned int*)alloc(256);
  int* degcnt = (int*)alloc(8192 * 4);
  float* ubuf  = (float*)alloc(8192 * 4);
  float* vbuf  = (float*)alloc(8192 * 4);
  float* scbuf = (float*)alloc(8192 * 4);
  float* o1buf = (float*)alloc(8192 * 4);
  unsigned long long* Awords = (unsigned long long*)alloc((size_t)8192 * 128 * 8);
  unsigned long long* AT     = (unsigned long long*)alloc((size_t)8192 * 128 * 8);
  short* h0F  = (short*)alloc((size_t)8192 * 256 * 2);
  short* h0BF = (short*)alloc((size_t)8192 * 256 * 2);
  short* h1F  = (short*)alloc((size_t)8192 * 256 * 2);
  short* h1BF = (short*)alloc((size_t)8192 * 256 * 2);
  short* h2   = (short*)alloc((size_t)8192 * 256 * 2);
  short* aggF = (short*)alloc((size_t)8192 * 256 * 2);
  const size_t SLICE = (size_t)8192 * 256 * 2;
  int nsplit = (ws_size >= off + 8 * SLICE + 4096) ? 8
             : (ws_size >= off + 4 * SLICE + 4096) ? 4 : 2;
  short* partials = (short*)alloc((size_t)nsplit * SLICE);
  const int ksplit = 8192 / nsplit;

  hipMemsetAsync(hist1, 0, NHC * 4096 * 4 + 8192 * 4 + 256 + 8192 * 4, stream);
  prep_kernel<<<1280, 256, 0, stream>>>(x, w_in, h1_wl, h1_wr, h2_wl, h2_wr,
                                        xbF, xnF, w_inF, w1lF, w1rF, w2lF, w2rF);
  hist0_kernel<<<688, 256, 0, stream>>>(xnF, hist1, sel);
  sim_kernel<1><<<NTRI / 4, 256, 0, stream>>>(xnF, hist2, sel, nullptr, nullptr, nullptr);
  sim_kernel<2><<<NTRI / 4, 256, 0, stream>>>(xnF, nullptr, sel, Awords, AT, degcnt);

  // h0 = relu(x @ w_in + b_in)  -> h0F (A-layout) + h0BF (B-layout)
  lin_kernel<false, true, false, true, true, false>
      <<<dim3(128, 4), 256, 0, stream>>>(xbF, w_inF, 128, nullptr, nullptr, 0,
                                         b_in, nullptr, h0F, h0BF, nullptr);
  // h1 = relu(agg(h0)@h1_wl + h1_bl + h0@h1_wr)  -> h1F + h1BF
  aggA_kernel<<<dim3(64, 2, nsplit), 256, 0, stream>>>(AT, h0BF, partials, ksplit);
  combine_kernel<<<1024, 256, 0, stream>>>(partials, nsplit, degcnt, aggF);
  lin_kernel<true, true, false, true, true, false>
      <<<dim3(128, 4), 256, 0, stream>>>(aggF, w1lF, 256, h0F, w1rF, 256,
                                         h1_bl, nullptr, h1F, h1BF, nullptr);
  // h2 = relu(agg(h1)@h2_wl + h2_bl + h1@h2_wr + h0)  -> h2 row-major
  aggA_kernel<<<dim3(64, 2, nsplit), 256, 0, stream>>>(AT, h1BF, partials, ksplit);
  combine_kernel<<<1024, 256, 0, stream>>>(partials, nsplit, degcnt, aggF);
  lin_kernel<true, true, true, false, false, true>
      <<<dim3(128, 4), 256, 0, stream>>>(aggF, w2lF, 256, h1F, w2rF, 256,
                                         h2_bl, h0F, nullptr, nullptr, h2);
  // output block
  vec3_kernel<<<2048, 256, 0, stream>>>(h2, o1_wl, o1_wr, osc_w, osc_b, ubuf, vbuf, scbuf);
  aggv1_kernel<<<2048, 256, 0, stream>>>(Awords, ubuf, degcnt, vbuf, o1_bl, o1buf);
  aggv2_kernel<<<2048, 256, 0, stream>>>(Awords, o1buf, degcnt, o2_wl, o2_bl, o2_wr, scbuf, out);
}

// Round 15
// 300.479 us; speedup vs baseline: 1.5562x; 1.5562x over previous
//
#include <hip/hip_runtime.h>

// GNN_79937931313503: dynamic-graph SAGE GNN on MI355X.
// R15: revert R14's inline-scan/threadfence pattern (156us stall in sim<1>).
// Back to R13 structure; keep merged prep_kernel and aggA running pointers.

typedef __attribute__((ext_vector_type(8))) short s8v;   // 8 x bf16 (4 VGPR)
typedef __attribute__((ext_vector_type(4))) float f4v;   // MFMA C/D frag

__device__ __forceinline__ f4v MFMA(s8v a, s8v b, f4v c) {
  return __builtin_amdgcn_mfma_f32_16x16x32_bf16(a, b, c, 0, 0, 0);
}
__device__ __forceinline__ short f2bf(float f) {  // RNE float->bf16 bits
  unsigned u = __float_as_uint(f);
  return (short)((u + 0x7FFFu + ((u >> 16) & 1u)) >> 16);
}
__device__ __forceinline__ float bf2f(short s) {
  return __uint_as_float(((unsigned)(unsigned short)s) << 16);
}

#define NT64 128
#define NTRI 8256  // 128*129/2
#define NHC 8      // global histogram copies

__device__ __forceinline__ void tri_invert(int t, int& r, int& c) {
  int rr = (int)((257.0f - sqrtf((float)(257 * 257 - 8 * t))) * 0.5f);
  if (rr < 0) rr = 0;
  if (rr > 127) rr = 127;
  while (rr < 127 && ((rr + 1) * NT64 - (rr + 1) * rr / 2) <= t) ++rr;
  while (rr > 0 && (rr * NT64 - rr * (rr - 1) / 2) > t) --rr;
  r = rr;
  c = rr + (t - (rr * NT64 - rr * (rr - 1) / 2));
}

// A-layout (F): chunk (row>>4, k>>5)*512; elem (m,k) at lane=((k>>3)&3)*16+m, e=k&7
// B-layout (BF): chunk (feat>>4)*256+(node>>5); elem at lane=((node>>3)&3)*16+feat&15

// ---------------- prep: x (blocks 0..127) + weights (blocks 128..1279) ------
__global__ __launch_bounds__(256) void prep_kernel(
    const float* __restrict__ x, const float* __restrict__ w_in,
    const float* __restrict__ w1l, const float* __restrict__ w1r,
    const float* __restrict__ w2l, const float* __restrict__ w2r,
    short* __restrict__ xbF, short* __restrict__ xnF, short* __restrict__ w_inF,
    short* __restrict__ w1lF, short* __restrict__ w1rF,
    short* __restrict__ w2lF, short* __restrict__ w2rF) {
  if (blockIdx.x < 128) {
    const int w = threadIdx.x >> 6, lane = threadIdx.x & 63;
    const int rg = blockIdx.x * 4 + w;
    const int m = lane & 15, g = lane >> 4;
    const int row = rg * 16 + m;
    float v[4][8];
    float ss = 0.f;
#pragma unroll
    for (int kc = 0; kc < 4; ++kc) {
      const float* src = x + row * 128 + kc * 32 + g * 8;
      float4 a = *(const float4*)src;
      float4 b = *(const float4*)(src + 4);
      v[kc][0] = a.x; v[kc][1] = a.y; v[kc][2] = a.z; v[kc][3] = a.w;
      v[kc][4] = b.x; v[kc][5] = b.y; v[kc][6] = b.z; v[kc][7] = b.w;
#pragma unroll
      for (int e = 0; e < 8; ++e) ss += v[kc][e] * v[kc][e];
    }
    ss += __shfl_xor(ss, 16);
    ss += __shfl_xor(ss, 32);
    float inv = 1.0f / fmaxf(sqrtf(ss), 1e-8f);
#pragma unroll
    for (int kc = 0; kc < 4; ++kc) {
      s8v raw, nrm;
#pragma unroll
      for (int e = 0; e < 8; ++e) {
        raw[e] = f2bf(v[kc][e]);
        nrm[e] = f2bf(v[kc][e] * inv);
      }
      *(s8v*)(xbF + (rg * 4 + kc) * 512 + lane * 8) = raw;
      *(s8v*)(xnF + (rg * 4 + kc) * 512 + lane * 8) = nrm;
    }
    return;
  }
  int idx = (blockIdx.x - 128) * 256 + threadIdx.x;
  if (idx >= 294912) return;
  if (idx < 32768) {                       // w_in [128k][256n], K=128
    int n = idx >> 7, k = idx & 127;
    size_t pos = (size_t)((n >> 4) * 4 + (k >> 5)) * 512 +
                 (((k >> 3) & 3) * 16 + (n & 15)) * 8 + (k & 7);
    w_inF[pos] = f2bf(w_in[k * 256 + n]);
  } else {
    int j = idx - 32768;
    int m = j >> 16, r = j & 65535;
    int n = r >> 8, k = r & 255;
    const float* src = (m == 0) ? w1l : (m == 1) ? w1r : (m == 2) ? w2l : w2r;
    short* dst = (m == 0) ? w1lF : (m == 1) ? w1rF : (m == 2) ? w2lF : w2rF;
    size_t pos = (size_t)((n >> 4) * 8 + (k >> 5)) * 512 +
                 (((k >> 3) & 3) * 16 + (n & 15)) * 8 + (k & 7);
    dst[pos] = f2bf(src[k * 256 + n]);
  }
}

// ---------------- hist0: persistent grid-stride linear histogram ----------
__global__ __launch_bounds__(256) void hist0_kernel(const short* __restrict__ xnF,
                                                    unsigned int* __restrict__ hist) {
  __shared__ unsigned int lh[4096];
  const int tid = threadIdx.x, w = tid >> 6, lane = tid & 63;
  for (int b = tid; b < 4096; b += 256) lh[b] = 0;
  __syncthreads();

  for (int tg = blockIdx.x; tg < NTRI / 4; tg += gridDim.x) {
    int t = tg * 4 + w;
    int r, c;
    tri_invert(t, r, c);
    const bool diag = (r == c);
    f4v acc[4][4];
#pragma unroll
    for (int a = 0; a < 4; ++a)
#pragma unroll
      for (int b = 0; b < 4; ++b) acc[a][b] = (f4v){0.f, 0.f, 0.f, 0.f};
    const int rga = r * 4, rgb = c * 4;
#pragma unroll
    for (int kc = 0; kc < 4; ++kc) {
      s8v af[4], bf[4];
#pragma unroll
      for (int mt = 0; mt < 4; ++mt)
        af[mt] = *(const s8v*)(xnF + ((rga + mt) * 4 + kc) * 512 + lane * 8);
#pragma unroll
      for (int nt = 0; nt < 4; ++nt)
        bf[nt] = *(const s8v*)(xnF + ((rgb + nt) * 4 + kc) * 512 + lane * 8);
#pragma unroll
      for (int mt = 0; mt < 4; ++mt)
#pragma unroll
        for (int nt = 0; nt < 4; ++nt) acc[mt][nt] = MFMA(af[mt], bf[nt], acc[mt][nt]);
    }
    unsigned wgt = diag ? 1u : 2u;
#pragma unroll
    for (int mt = 0; mt < 4; ++mt)
      for (int nt = 0; nt < 4; ++nt)
        for (int rr = 0; rr < 4; ++rr) {
          float val = fabsf(acc[mt][nt][rr]);
          int bin = (int)(val * 4096.0f);
          bin = min(max(bin, 0), 4095);
          atomicAdd(&lh[bin], wgt);
        }
  }
  __syncthreads();
  unsigned int* hc = hist + (blockIdx.x & (NHC - 1)) * 4096;
  for (int b = tid; b < 4096; b += 256)
    if (lh[b]) atomicAdd(&hc[b], lh[b]);
}

// ---------------- sim: per-wave 64x64 tiles, upper triangle only ----------------
template <int MODE>
__global__ __launch_bounds__(256) void sim_kernel(
    const short* __restrict__ xnF, unsigned int* __restrict__ hist,
    unsigned int* __restrict__ sel, unsigned long long* __restrict__ Awords,
    unsigned long long* __restrict__ AT) {
  const int tid = threadIdx.x, w = tid >> 6, lane = tid & 63;
  int t = blockIdx.x * 4 + w;
  int r, c;
  tri_invert(t, r, c);
  const int i0 = r * 64, j0 = c * 64;
  const bool diag = (r == c);

  f4v acc[4][4];
#pragma unroll
  for (int a = 0; a < 4; ++a)
#pragma unroll
    for (int b = 0; b < 4; ++b) acc[a][b] = (f4v){0.f, 0.f, 0.f, 0.f};

  const int rga = r * 4, rgb = c * 4;
#pragma unroll
  for (int kc = 0; kc < 4; ++kc) {
    s8v af[4], bf[4];
#pragma unroll
    for (int mt = 0; mt < 4; ++mt)
      af[mt] = *(const s8v*)(xnF + ((rga + mt) * 4 + kc) * 512 + lane * 8);
#pragma unroll
    for (int nt = 0; nt < 4; ++nt)
      bf[nt] = *(const s8v*)(xnF + ((rgb + nt) * 4 + kc) * 512 + lane * 8);
#pragma unroll
    for (int mt = 0; mt < 4; ++mt)
#pragma unroll
      for (int nt = 0; nt < 4; ++nt) acc[mt][nt] = MFMA(af[mt], bf[nt], acc[mt][nt]);
  }

  if (MODE == 1) {
    int pref = (int)sel[0];
    unsigned wgt = diag ? 1u : 2u;
#pragma unroll
    for (int mt = 0; mt < 4; ++mt)
      for (int nt = 0; nt < 4; ++nt)
        for (int rr = 0; rr < 4; ++rr) {
          float tt = fabsf(acc[mt][nt][rr]) * 4096.0f;
          int bin = min(max((int)tt, 0), 4095);
          if (bin == pref) {
            int b2 = (int)((tt - (float)pref) * 8192.0f);
            b2 = min(max(b2, 0), 8191);
            atomicAdd(&hist[b2], wgt);
          }
        }
  } else {
    float eps = __uint_as_float(sel[2]);
    unsigned long long myword = 0;  // lane j holds row (i0+j)'s bits [j0..j0+64)
#pragma unroll
    for (int mt = 0; mt < 4; ++mt)
#pragma unroll
      for (int rr = 0; rr < 4; ++rr) {
        unsigned long long b0 = __ballot(fabsf(acc[mt][0][rr]) >= eps);
        unsigned long long b1 = __ballot(fabsf(acc[mt][1][rr]) >= eps);
        unsigned long long b2 = __ballot(fabsf(acc[mt][2][rr]) >= eps);
        unsigned long long b3 = __ballot(fabsf(acc[mt][3][rr]) >= eps);
        if ((lane >> 4) == mt && (lane & 3) == rr) {
          int gj = (lane >> 2) & 3;
          myword = ((b0 >> (16 * gj)) & 0xFFFFull) |
                   (((b1 >> (16 * gj)) & 0xFFFFull) << 16) |
                   (((b2 >> (16 * gj)) & 0xFFFFull) << 32) |
                   (((b3 >> (16 * gj)) & 0xFFFFull) << 48);
        }
      }
    Awords[(size_t)(i0 + lane) * 128 + (j0 >> 6)] = myword;
    AT[(size_t)(j0 >> 6) * 8192 + i0 + lane] = myword;
    if (!diag) {  // mirrored tile via 64x64 bit transpose (ballot per column)
      unsigned long long tw = 0;
#pragma unroll
      for (int c2 = 0; c2 < 64; ++c2) {
        unsigned long long bc = __ballot((myword >> c2) & 1ull);
        if (lane == c2) tw = bc;
      }
      Awords[(size_t)(j0 + lane) * 128 + (i0 >> 6)] = tw;
      AT[(size_t)(i0 >> 6) * 8192 + j0 + lane] = tw;
    }
  }
}

// ---------------- histogram selection scan ----------------
template <int NB, int MODE>
__global__ __launch_bounds__(256) void scan_kernel(const unsigned int* __restrict__ hist,
                                                   unsigned int* __restrict__ sel) {
  __shared__ unsigned long long csum[256];
  const int t = threadIdx.x;
  const int PER = NB / 256;
  unsigned int vals[NB / 256];
  unsigned long long s = 0;
  for (int i = 0; i < PER; ++i) {
    unsigned v = 0;
    if (MODE == 0) {
      for (int cc = 0; cc < NHC; ++cc) v += hist[cc * NB + t * PER + i];
    } else {
      v = hist[t * PER + i];
    }
    vals[i] = v;
    s += v;
  }
  csum[t] = s;
  __syncthreads();
  for (int o = 1; o < 256; o <<= 1) {
    unsigned long long prev = (t >= o) ? csum[t - o] : 0ull;
    __syncthreads();
    csum[t] += prev;
    __syncthreads();
  }
  unsigned long long K = (MODE == 0) ? 63753421ull : (unsigned long long)sel[1];
  unsigned long long inc = csum[t], exc = inc - s;
  if (K > exc && K <= inc) {
    unsigned long long c = exc;
    for (int i = 0; i < PER; ++i) {
      c += vals[i];
      if (c >= K) {
        if (MODE == 0) {
          sel[0] = (unsigned)(t * PER + i);
          sel[1] = (unsigned)(K - (c - vals[i]));
        } else {
          float eps = ((float)sel[0] + (float)(t * PER + i) * (1.0f / 8192.0f)) *
                      (1.0f / 4096.0f);
          sel[2] = __float_as_uint(eps);
        }
        break;
      }
    }
  }
}

// ---------------- degree ----------------
__global__ __launch_bounds__(256) void deg_kernel(const unsigned long long* __restrict__ Awords,
                                                  float* __restrict__ deg_inv) {
  int row = blockIdx.x * 4 + (threadIdx.x >> 6);
  int lane = threadIdx.x & 63;
  int c = __popcll(Awords[row * 128 + lane]) + __popcll(Awords[row * 128 + 64 + lane]);
  for (int o = 32; o; o >>= 1) c += __shfl_down(c, o);
  if (lane == 0) deg_inv[row] = 1.0f / (float)max(c, 1);
}

// ---------------- lin: F-layout GEMM ----------------------------------------
template <bool TWO, bool RELU, bool RES, bool WF, bool WBF, bool WRM>
__global__ __launch_bounds__(256) void lin_kernel(
    const short* __restrict__ A1, const short* __restrict__ B1, int K1,
    const short* __restrict__ A2, const short* __restrict__ B2, int K2,
    const float* __restrict__ bias, const short* __restrict__ resF,
    short* __restrict__ outF, short* __restrict__ outBF, short* __restrict__ outRM) {
  const int i0 = blockIdx.x * 64, n0 = blockIdx.y * 64;
  const int tid = threadIdx.x, w = tid >> 6, lane = tid & 63;
  const int wy = (w >> 1) * 32, wx = (w & 1) * 32;
  f4v acc[2][2];
#pragma unroll
  for (int a = 0; a < 2; ++a)
#pragma unroll
    for (int b = 0; b < 2; ++b) acc[a][b] = (f4v){0.f, 0.f, 0.f, 0.f};

  const int ka = K1 >> 5;
  const int ra0 = (i0 + wy) >> 4, rb0 = (n0 + wx) >> 4;
  for (int cc = 0; cc < ka; ++cc) {
    s8v a0 = *(const s8v*)(A1 + ((ra0 + 0) * ka + cc) * 512 + lane * 8);
    s8v a1 = *(const s8v*)(A1 + ((ra0 + 1) * ka + cc) * 512 + lane * 8);
    s8v b0 = *(const s8v*)(B1 + ((rb0 + 0) * ka + cc) * 512 + lane * 8);
    s8v b1 = *(const s8v*)(B1 + ((rb0 + 1) * ka + cc) * 512 + lane * 8);
    acc[0][0] = MFMA(a0, b0, acc[0][0]);
    acc[0][1] = MFMA(a0, b1, acc[0][1]);
    acc[1][0] = MFMA(a1, b0, acc[1][0]);
    acc[1][1] = MFMA(a1, b1, acc[1][1]);
  }
  if constexpr (TWO) {
    const int kb = K2 >> 5;
    for (int cc = 0; cc < kb; ++cc) {
      s8v a0 = *(const s8v*)(A2 + ((ra0 + 0) * kb + cc) * 512 + lane * 8);
      s8v a1 = *(const s8v*)(A2 + ((ra0 + 1) * kb + cc) * 512 + lane * 8);
      s8v b0 = *(const s8v*)(B2 + ((rb0 + 0) * kb + cc) * 512 + lane * 8);
      s8v b1 = *(const s8v*)(B2 + ((rb0 + 1) * kb + cc) * 512 + lane * 8);
      acc[0][0] = MFMA(a0, b0, acc[0][0]);
      acc[0][1] = MFMA(a0, b1, acc[0][1]);
      acc[1][0] = MFMA(a1, b0, acc[1][0]);
      acc[1][1] = MFMA(a1, b1, acc[1][1]);
    }
  }
#pragma unroll
  for (int mt = 0; mt < 2; ++mt)
#pragma unroll
    for (int nt = 0; nt < 2; ++nt)
#pragma unroll
      for (int rr = 0; rr < 4; ++rr) {
        int row = i0 + wy + mt * 16 + (lane >> 4) * 4 + rr;
        int col = n0 + wx + nt * 16 + (lane & 15);
        float v = acc[mt][nt][rr] + bias[col];
        if constexpr (RES) {
          v += bf2f(resF[(size_t)((row >> 4) * 8 + (col >> 5)) * 512 +
                         (((col >> 3) & 3) * 16 + (row & 15)) * 8 + (col & 7)]);
        }
        if constexpr (RELU) v = fmaxf(v, 0.f);
        short sv = f2bf(v);
        if constexpr (WRM) outRM[row * 256 + col] = sv;
        if constexpr (WF) {
          outF[(size_t)((row >> 4) * 8 + (col >> 5)) * 512 +
               (((col >> 3) & 3) * 16 + (row & 15)) * 8 + (col & 7)] = sv;
        }
        if constexpr (WBF) {
          outBF[(size_t)((col >> 4) * 256 + (row >> 5)) * 512 +
                (((row >> 3) & 3) * 16 + (col & 15)) * 8 + (row & 7)] = sv;
        }
      }
}

// ---------------- aggA: partialF[z] = Fmajor(A[:, kslice] @ h[kslice, :]) ----
__global__ __launch_bounds__(256, 3) void aggA_kernel(
    const unsigned long long* __restrict__ AT, const short* __restrict__ hBF,
    short* __restrict__ partial, int ksplit) {
  const int i0 = blockIdx.x * 128;
  const int f0 = blockIdx.y * 128;
  const int k0 = blockIdx.z * ksplit;
  const int tid = threadIdx.x, w = tid >> 6, lane = tid & 63;
  const int wy = (w >> 1) * 64, wx = f0 + (w & 1) * 64;
  const int lr = lane & 15, g = lane >> 4, g8 = g * 8;

  f4v acc[4][4];
#pragma unroll
  for (int a = 0; a < 4; ++a)
#pragma unroll
    for (int b = 0; b < 4; ++b) acc[a][b] = (f4v){0.f, 0.f, 0.f, 0.f};

  const unsigned long long* awp = AT + (size_t)(k0 >> 6) * 8192 + i0 + wy + lr;
  const short* bp0 = hBF + ((size_t)(wx >> 4) * 256 + (k0 >> 5)) * 512 + lane * 8;
  const short* bp1 = bp0 + 131072;   // +1 chunk-row of 256*512 shorts
  const short* bp2 = bp0 + 262144;
  const short* bp3 = bp0 + 393216;

  for (int kb = 0; kb < ksplit; kb += 64) {
    unsigned long long aw[4];
#pragma unroll
    for (int mt = 0; mt < 4; ++mt) aw[mt] = awp[mt * 16];
#pragma unroll
    for (int kc = 0; kc < 2; ++kc) {
      s8v bf[4];
      bf[0] = *(const s8v*)(bp0 + kc * 512);
      bf[1] = *(const s8v*)(bp1 + kc * 512);
      bf[2] = *(const s8v*)(bp2 + kc * 512);
      bf[3] = *(const s8v*)(bp3 + kc * 512);
#pragma unroll
      for (int mt = 0; mt < 4; ++mt) {
        unsigned byte = ((unsigned)(aw[mt] >> (kc * 32)) >> g8) & 0xFFu;
        unsigned adv[4];
        adv[0] = ((byte & 1u) | ((byte & 2u) << 15)) * 0x3F80u;
        adv[1] = (((byte >> 2) & 1u) | (((byte >> 2) & 2u) << 15)) * 0x3F80u;
        adv[2] = (((byte >> 4) & 1u) | (((byte >> 4) & 2u) << 15)) * 0x3F80u;
        adv[3] = (((byte >> 6) & 1u) | (((byte >> 6) & 2u) << 15)) * 0x3F80u;
        s8v a;
        __builtin_memcpy(&a, adv, 16);
#pragma unroll
        for (int nt = 0; nt < 4; ++nt) acc[mt][nt] = MFMA(a, bf[nt], acc[mt][nt]);
      }
    }
    awp += 8192;
    bp0 += 1024; bp1 += 1024; bp2 += 1024; bp3 += 1024;
  }
  short* P = partial + (size_t)blockIdx.z * 2097152;
#pragma unroll
  for (int mt = 0; mt < 4; ++mt)
#pragma unroll
    for (int nt = 0; nt < 4; ++nt)
#pragma unroll
      for (int rr = 0; rr < 4; ++rr) {
        int row = i0 + wy + mt * 16 + g * 4 + rr;
        int col = wx + nt * 16 + lr;
        P[(size_t)((row >> 4) * 8 + (col >> 5)) * 512 +
          (((col >> 3) & 3) * 16 + (row & 15)) * 8 + (col & 7)] = f2bf(acc[mt][nt][rr]);
      }
}

// combine: aggF = bf16((sum_z partialF[z]) * deg_inv[row]); A-layout in+out
__global__ __launch_bounds__(256) void combine_kernel(const short* __restrict__ p, int nsplit,
                                                      const float* __restrict__ deg_inv,
                                                      short* __restrict__ aggF) {
  int idx8 = blockIdx.x * 256 + threadIdx.x;  // one s8v group in A-layout
  float s[8];
#pragma unroll
  for (int e = 0; e < 8; ++e) s[e] = 0.f;
  for (int k = 0; k < nsplit; ++k) {
    s8v v = *(const s8v*)(p + (size_t)k * 2097152 + (size_t)idx8 * 8);
#pragma unroll
    for (int e = 0; e < 8; ++e) s[e] += bf2f(v[e]);
  }
  int chunk = idx8 >> 6, lane = idx8 & 63;
  int row = (chunk >> 3) * 16 + (lane & 15);
  float di = deg_inv[row];
  s8v o;
#pragma unroll
  for (int e = 0; e < 8; ++e) o[e] = f2bf(s[e] * di);
  *(s8v*)(aggF + (size_t)idx8 * 8) = o;
}

// ---------------- tail ----------------
__global__ __launch_bounds__(256) void vec3_kernel(const short* __restrict__ h2,
                                                   const float* __restrict__ o1wl,
                                                   const float* __restrict__ o1wr,
                                                   const float* __restrict__ oscw,
                                                   const float* __restrict__ oscb,
                                                   float* __restrict__ u, float* __restrict__ v,
                                                   float* __restrict__ sc) {
  int row = blockIdx.x * 4 + (threadIdx.x >> 6);
  int lane = threadIdx.x & 63;
  float su = 0.f, sv = 0.f, ss = 0.f;
#pragma unroll
  for (int e = 0; e < 4; ++e) {
    int k = lane * 4 + e;
    float hv = bf2f(h2[row * 256 + k]);
    su += hv * o1wl[k];
    sv += hv * o1wr[k];
    ss += hv * oscw[k];
  }
  for (int o = 1; o < 64; o <<= 1) {
    su += __shfl_xor(su, o);
    sv += __shfl_xor(sv, o);
    ss += __shfl_xor(ss, o);
  }
  if (lane == 0) {
    u[row] = su;
    v[row] = sv;
    sc[row] = ss + oscb[0];
  }
}

__global__ __launch_bounds__(256) void aggv1_kernel(const unsigned long long* __restrict__ Awords,
                                                    const float* __restrict__ u,
                                                    const float* __restrict__ deg_inv,
                                                    const float* __restrict__ v,
                                                    const float* __restrict__ o1bl,
                                                    float* __restrict__ o1) {
  int row = blockIdx.x * 4 + (threadIdx.x >> 6);
  int lane = threadIdx.x & 63;
  float s = 0.f;
#pragma unroll
  for (int wi = 0; wi < 2; ++wi) {
    unsigned long long bits = Awords[row * 128 + wi * 64 + lane];
    int base = (wi * 64 + lane) * 64;
    while (bits) {
      int b = __ffsll(bits) - 1;
      s += u[base + b];
      bits &= bits - 1;
    }
  }
  for (int o = 1; o < 64; o <<= 1) s += __shfl_xor(s, o);
  if (lane == 0) o1[row] = fmaxf(s * deg_inv[row] + o1bl[0] + v[row], 0.f);
}

__global__ __launch_bounds__(256) void aggv2_kernel(const unsigned long long* __restrict__ Awords,
                                                    const float* __restrict__ o1,
                                                    const float* __restrict__ deg_inv,
                                                    const float* __restrict__ o2wl,
                                                    const float* __restrict__ o2bl,
                                                    const float* __restrict__ o2wr,
                                                    const float* __restrict__ sc,
                                                    float* __restrict__ out) {
  int row = blockIdx.x * 4 + (threadIdx.x >> 6);
  int lane = threadIdx.x & 63;
  float s = 0.f;
#pragma unroll
  for (int wi = 0; wi < 2; ++wi) {
    unsigned long long bits = Awords[row * 128 + wi * 64 + lane];
    int base = (wi * 64 + lane) * 64;
    while (bits) {
      int b = __ffsll(bits) - 1;
      s += o1[base + b];
      bits &= bits - 1;
    }
  }
  for (int o = 1; o < 64; o <<= 1) s += __shfl_xor(s, o);
  if (lane == 0) {
    float z = s * deg_inv[row] * o2wl[0] + o2bl[0] + o1[row] * o2wr[0] + sc[row];
    out[row] = 1.f / (1.f + expf(-z));
  }
}

// ---------------- launch ----------------
extern "C" void kernel_launch(void* const* d_in, const int* in_sizes, int n_in,
                              void* d_out, int out_size, void* d_ws, size_t ws_size,
                              hipStream_t stream) {
  (void)in_sizes; (void)n_in; (void)out_size;
  const float* x     = (const float*)d_in[0];
  const float* w_in  = (const float*)d_in[1];
  const float* b_in  = (const float*)d_in[2];
  const float* h1_wl = (const float*)d_in[3];
  const float* h1_bl = (const float*)d_in[4];
  const float* h1_wr = (const float*)d_in[5];
  const float* h2_wl = (const float*)d_in[6];
  const float* h2_bl = (const float*)d_in[7];
  const float* h2_wr = (const float*)d_in[8];
  const float* o1_wl = (const float*)d_in[9];
  const float* o1_bl = (const float*)d_in[10];
  const float* o1_wr = (const float*)d_in[11];
  const float* o2_wl = (const float*)d_in[12];
  const float* o2_bl = (const float*)d_in[13];
  const float* o2_wr = (const float*)d_in[14];
  const float* osc_w = (const float*)d_in[15];
  const float* osc_b = (const float*)d_in[16];
  float* out = (float*)d_out;

  char* ws = (char*)d_ws;
  size_t off = 0;
  auto alloc = [&](size_t bytes) -> char* {
    char* p = ws + off;
    off += (bytes + 255) & ~(size_t)255;
    return p;
  };
  short* xnF   = (short*)alloc(8192 * 128 * 2);
  short* xbF   = (short*)alloc(8192 * 128 * 2);
  short* w_inF = (short*)alloc(256 * 128 * 2);
  short* w1lF  = (short*)alloc(256 * 256 * 2);
  short* w1rF  = (short*)alloc(256 * 256 * 2);
  short* w2lF  = (short*)alloc(256 * 256 * 2);
  short* w2rF  = (short*)alloc(256 * 256 * 2);
  unsigned int* hist1 = (unsigned int*)alloc(NHC * 4096 * 4);
  unsigned int* hist2 = (unsigned int*)alloc(8192 * 4);
  unsigned int* sel   = (unsigned int*)alloc(256);
  float* deg_inv = (float*)alloc(8192 * 4);
  float* ubuf  = (float*)alloc(8192 * 4);
  float* vbuf  = (float*)alloc(8192 * 4);
  float* scbuf = (float*)alloc(8192 * 4);
  float* o1buf = (float*)alloc(8192 * 4);
  unsigned long long* Awords = (unsigned long long*)alloc((size_t)8192 * 128 * 8);
  unsigned long long* AT     = (unsigned long long*)alloc((size_t)8192 * 128 * 8);
  short* h0F  = (short*)alloc((size_t)8192 * 256 * 2);
  short* h0BF = (short*)alloc((size_t)8192 * 256 * 2);
  short* h1F  = (short*)alloc((size_t)8192 * 256 * 2);
  short* h1BF = (short*)alloc((size_t)8192 * 256 * 2);
  short* h2   = (short*)alloc((size_t)8192 * 256 * 2);
  short* aggF = (short*)alloc((size_t)8192 * 256 * 2);
  const size_t SLICE = (size_t)8192 * 256 * 2;
  int nsplit = (ws_size >= off + 8 * SLICE + 4096) ? 8
             : (ws_size >= off + 4 * SLICE + 4096) ? 4 : 2;
  short* partials = (short*)alloc((size_t)nsplit * SLICE);
  const int ksplit = 8192 / nsplit;

  hipMemsetAsync(hist1, 0, (NHC * 4096 + 8192) * 4, stream);
  prep_kernel<<<1280, 256, 0, stream>>>(x, w_in, h1_wl, h1_wr, h2_wl, h2_wr,
                                        xbF, xnF, w_inF, w1lF, w1rF, w2lF, w2rF);
  hist0_kernel<<<688, 256, 0, stream>>>(xnF, hist1);
  scan_kernel<4096, 0><<<1, 256, 0, stream>>>(hist1, sel);
  sim_kernel<1><<<NTRI / 4, 256, 0, stream>>>(xnF, hist2, sel, nullptr, nullptr);
  scan_kernel<8192, 1><<<1, 256, 0, stream>>>(hist2, sel);
  sim_kernel<2><<<NTRI / 4, 256, 0, stream>>>(xnF, nullptr, sel, Awords, AT);
  deg_kernel<<<2048, 256, 0, stream>>>(Awords, deg_inv);

  // h0 = relu(x @ w_in + b_in)  -> h0F (A-layout) + h0BF (B-layout)
  lin_kernel<false, true, false, true, true, false>
      <<<dim3(128, 4), 256, 0, stream>>>(xbF, w_inF, 128, nullptr, nullptr, 0,
                                         b_in, nullptr, h0F, h0BF, nullptr);
  // h1 = relu(agg(h0)@h1_wl + h1_bl + h0@h1_wr)  -> h1F + h1BF
  aggA_kernel<<<dim3(64, 2, nsplit), 256, 0, stream>>>(AT, h0BF, partials, ksplit);
  combine_kernel<<<1024, 256, 0, stream>>>(partials, nsplit, deg_inv, aggF);
  lin_kernel<true, true, false, true, true, false>
      <<<dim3(128, 4), 256, 0, stream>>>(aggF, w1lF, 256, h0F, w1rF, 256,
                                         h1_bl, nullptr, h1F, h1BF, nullptr);
  // h2 = relu(agg(h1)@h2_wl + h2_bl + h1@h2_wr + h0)  -> h2 row-major
  aggA_kernel<<<dim3(64, 2, nsplit), 256, 0, stream>>>(AT, h1BF, partials, ksplit);
  combine_kernel<<<1024, 256, 0, stream>>>(partials, nsplit, deg_inv, aggF);
  lin_kernel<true, true, true, false, false, true>
      <<<dim3(128, 4), 256, 0, stream>>>(aggF, w2lF, 256, h1F, w2rF, 256,
                                         h2_bl, h0F, nullptr, nullptr, h2);
  // output block
  vec3_kernel<<<2048, 256, 0, stream>>>(h2, o1_wl, o1_wr, osc_w, osc_b, ubuf, vbuf, scbuf);
  aggv1_kernel<<<2048, 256, 0, stream>>>(Awords, ubuf, deg_inv, vbuf, o1_bl, o1buf);
  aggv2_kernel<<<2048, 256, 0, stream>>>(Awords, o1buf, deg_inv, o2_wl, o2_bl, o2_wr, scbuf, out);
}

// Round 16
// 299.170 us; speedup vs baseline: 1.5630x; 1.0044x over previous
//
#include <hip/hip_runtime.h>

// GNN_79937931313503: dynamic-graph SAGE GNN on MI355X.
// R16: aggA switched to fp8 MFMA (mfma_f32_16x16x32_fp8_fp8). A bits expand
// to e4m3 0/1 (2 dwords, mul-spread 0x38); B = h post-relu quantized to e4m3
// in lin's epilogue (hBF8). Halves aggA's B L1-return traffic and expansion
// VALU at identical MFMA rate. Everything else = R15.

typedef __attribute__((ext_vector_type(8))) short s8v;   // 8 x bf16 (4 VGPR)
typedef __attribute__((ext_vector_type(4))) float f4v;   // MFMA C/D frag
typedef long long i64t;                                  // fp8 MFMA operand

__device__ __forceinline__ f4v MFMA(s8v a, s8v b, f4v c) {
  return __builtin_amdgcn_mfma_f32_16x16x32_bf16(a, b, c, 0, 0, 0);
}
__device__ __forceinline__ f4v MFMA8(i64t a, i64t b, f4v c) {
  return __builtin_amdgcn_mfma_f32_16x16x32_fp8_fp8(a, b, c, 0, 0, 0);
}
__device__ __forceinline__ short f2bf(float f) {  // RNE float->bf16 bits
  unsigned u = __float_as_uint(f);
  return (short)((u + 0x7FFFu + ((u >> 16) & 1u)) >> 16);
}
__device__ __forceinline__ float bf2f(short s) {
  return __uint_as_float(((unsigned)(unsigned short)s) << 16);
}
// RNE float -> OCP e4m3fn byte
__device__ __forceinline__ unsigned char f2e4m3(float f) {
  unsigned u = __float_as_uint(f);
  unsigned sign = (u >> 24) & 0x80u;
  unsigned a = u & 0x7FFFFFFFu;
  if (a >= 0x43E00000u) return (unsigned char)(sign | 0x7Eu);  // clamp 448
  if (a < 0x3C800000u) {  // below 2^-6: denormal units of 2^-9
    unsigned n = (unsigned)rintf(__uint_as_float(a) * 512.0f);
    return (unsigned char)(sign | n);  // n==8 -> 0x08 == 2^-6 exactly
  }
  unsigned r = a + 0x7FFFFu + ((a >> 20) & 1u);
  unsigned bits = (r >> 20) - 960u;
  if (bits > 0x7Eu) bits = 0x7Eu;
  return (unsigned char)(sign | bits);
}

#define NT64 128
#define NTRI 8256  // 128*129/2
#define NHC 8      // global histogram copies

__device__ __forceinline__ void tri_invert(int t, int& r, int& c) {
  int rr = (int)((257.0f - sqrtf((float)(257 * 257 - 8 * t))) * 0.5f);
  if (rr < 0) rr = 0;
  if (rr > 127) rr = 127;
  while (rr < 127 && ((rr + 1) * NT64 - (rr + 1) * rr / 2) <= t) ++rr;
  while (rr > 0 && (rr * NT64 - rr * (rr - 1) / 2) > t) --rr;
  r = rr;
  c = rr + (t - (rr * NT64 - rr * (rr - 1) / 2));
}

// A-layout (F): chunk (row>>4, k>>5)*512; elem (m,k) at lane=((k>>3)&3)*16+m, e=k&7
// B8-layout: fp8 chunk (feat>>4)*256+(node>>5), 512 B; lane=((node>>3)&3)*16+(feat&15), e=node&7

// ---------------- prep: x (blocks 0..127) + weights (blocks 128..1279) ------
__global__ __launch_bounds__(256) void prep_kernel(
    const float* __restrict__ x, const float* __restrict__ w_in,
    const float* __restrict__ w1l, const float* __restrict__ w1r,
    const float* __restrict__ w2l, const float* __restrict__ w2r,
    short* __restrict__ xbF, short* __restrict__ xnF, short* __restrict__ w_inF,
    short* __restrict__ w1lF, short* __restrict__ w1rF,
    short* __restrict__ w2lF, short* __restrict__ w2rF) {
  if (blockIdx.x < 128) {
    const int w = threadIdx.x >> 6, lane = threadIdx.x & 63;
    const int rg = blockIdx.x * 4 + w;
    const int m = lane & 15, g = lane >> 4;
    const int row = rg * 16 + m;
    float v[4][8];
    float ss = 0.f;
#pragma unroll
    for (int kc = 0; kc < 4; ++kc) {
      const float* src = x + row * 128 + kc * 32 + g * 8;
      float4 a = *(const float4*)src;
      float4 b = *(const float4*)(src + 4);
      v[kc][0] = a.x; v[kc][1] = a.y; v[kc][2] = a.z; v[kc][3] = a.w;
      v[kc][4] = b.x; v[kc][5] = b.y; v[kc][6] = b.z; v[kc][7] = b.w;
#pragma unroll
      for (int e = 0; e < 8; ++e) ss += v[kc][e] * v[kc][e];
    }
    ss += __shfl_xor(ss, 16);
    ss += __shfl_xor(ss, 32);
    float inv = 1.0f / fmaxf(sqrtf(ss), 1e-8f);
#pragma unroll
    for (int kc = 0; kc < 4; ++kc) {
      s8v raw, nrm;
#pragma unroll
      for (int e = 0; e < 8; ++e) {
        raw[e] = f2bf(v[kc][e]);
        nrm[e] = f2bf(v[kc][e] * inv);
      }
      *(s8v*)(xbF + (rg * 4 + kc) * 512 + lane * 8) = raw;
      *(s8v*)(xnF + (rg * 4 + kc) * 512 + lane * 8) = nrm;
    }
    return;
  }
  int idx = (blockIdx.x - 128) * 256 + threadIdx.x;
  if (idx >= 294912) return;
  if (idx < 32768) {                       // w_in [128k][256n], K=128
    int n = idx >> 7, k = idx & 127;
    size_t pos = (size_t)((n >> 4) * 4 + (k >> 5)) * 512 +
                 (((k >> 3) & 3) * 16 + (n & 15)) * 8 + (k & 7);
    w_inF[pos] = f2bf(w_in[k * 256 + n]);
  } else {
    int j = idx - 32768;
    int m = j >> 16, r = j & 65535;
    int n = r >> 8, k = r & 255;
    const float* src = (m == 0) ? w1l : (m == 1) ? w1r : (m == 2) ? w2l : w2r;
    short* dst = (m == 0) ? w1lF : (m == 1) ? w1rF : (m == 2) ? w2lF : w2rF;
    size_t pos = (size_t)((n >> 4) * 8 + (k >> 5)) * 512 +
                 (((k >> 3) & 3) * 16 + (n & 15)) * 8 + (k & 7);
    dst[pos] = f2bf(src[k * 256 + n]);
  }
}

// ---------------- hist0: persistent grid-stride linear histogram ----------
__global__ __launch_bounds__(256) void hist0_kernel(const short* __restrict__ xnF,
                                                    unsigned int* __restrict__ hist) {
  __shared__ unsigned int lh[4096];
  const int tid = threadIdx.x, w = tid >> 6, lane = tid & 63;
  for (int b = tid; b < 4096; b += 256) lh[b] = 0;
  __syncthreads();

  for (int tg = blockIdx.x; tg < NTRI / 4; tg += gridDim.x) {
    int t = tg * 4 + w;
    int r, c;
    tri_invert(t, r, c);
    const bool diag = (r == c);
    f4v acc[4][4];
#pragma unroll
    for (int a = 0; a < 4; ++a)
#pragma unroll
      for (int b = 0; b < 4; ++b) acc[a][b] = (f4v){0.f, 0.f, 0.f, 0.f};
    const int rga = r * 4, rgb = c * 4;
#pragma unroll
    for (int kc = 0; kc < 4; ++kc) {
      s8v af[4], bf[4];
#pragma unroll
      for (int mt = 0; mt < 4; ++mt)
        af[mt] = *(const s8v*)(xnF + ((rga + mt) * 4 + kc) * 512 + lane * 8);
#pragma unroll
      for (int nt = 0; nt < 4; ++nt)
        bf[nt] = *(const s8v*)(xnF + ((rgb + nt) * 4 + kc) * 512 + lane * 8);
#pragma unroll
      for (int mt = 0; mt < 4; ++mt)
#pragma unroll
        for (int nt = 0; nt < 4; ++nt) acc[mt][nt] = MFMA(af[mt], bf[nt], acc[mt][nt]);
    }
    unsigned wgt = diag ? 1u : 2u;
#pragma unroll
    for (int mt = 0; mt < 4; ++mt)
      for (int nt = 0; nt < 4; ++nt)
        for (int rr = 0; rr < 4; ++rr) {
          float val = fabsf(acc[mt][nt][rr]);
          int bin = (int)(val * 4096.0f);
          bin = min(max(bin, 0), 4095);
          atomicAdd(&lh[bin], wgt);
        }
  }
  __syncthreads();
  unsigned int* hc = hist + (blockIdx.x & (NHC - 1)) * 4096;
  for (int b = tid; b < 4096; b += 256)
    if (lh[b]) atomicAdd(&hc[b], lh[b]);
}

// ---------------- sim: per-wave 64x64 tiles, upper triangle only ----------------
template <int MODE>
__global__ __launch_bounds__(256) void sim_kernel(
    const short* __restrict__ xnF, unsigned int* __restrict__ hist,
    unsigned int* __restrict__ sel, unsigned long long* __restrict__ Awords,
    unsigned long long* __restrict__ AT) {
  const int tid = threadIdx.x, w = tid >> 6, lane = tid & 63;
  int t = blockIdx.x * 4 + w;
  int r, c;
  tri_invert(t, r, c);
  const int i0 = r * 64, j0 = c * 64;
  const bool diag = (r == c);

  f4v acc[4][4];
#pragma unroll
  for (int a = 0; a < 4; ++a)
#pragma unroll
    for (int b = 0; b < 4; ++b) acc[a][b] = (f4v){0.f, 0.f, 0.f, 0.f};

  const int rga = r * 4, rgb = c * 4;
#pragma unroll
  for (int kc = 0; kc < 4; ++kc) {
    s8v af[4], bf[4];
#pragma unroll
    for (int mt = 0; mt < 4; ++mt)
      af[mt] = *(const s8v*)(xnF + ((rga + mt) * 4 + kc) * 512 + lane * 8);
#pragma unroll
    for (int nt = 0; nt < 4; ++nt)
      bf[nt] = *(const s8v*)(xnF + ((rgb + nt) * 4 + kc) * 512 + lane * 8);
#pragma unroll
    for (int mt = 0; mt < 4; ++mt)
#pragma unroll
      for (int nt = 0; nt < 4; ++nt) acc[mt][nt] = MFMA(af[mt], bf[nt], acc[mt][nt]);
  }

  if (MODE == 1) {
    int pref = (int)sel[0];
    unsigned wgt = diag ? 1u : 2u;
#pragma unroll
    for (int mt = 0; mt < 4; ++mt)
      for (int nt = 0; nt < 4; ++nt)
        for (int rr = 0; rr < 4; ++rr) {
          float tt = fabsf(acc[mt][nt][rr]) * 4096.0f;
          int bin = min(max((int)tt, 0), 4095);
          if (bin == pref) {
            int b2 = (int)((tt - (float)pref) * 8192.0f);
            b2 = min(max(b2, 0), 8191);
            atomicAdd(&hist[b2], wgt);
          }
        }
  } else {
    float eps = __uint_as_float(sel[2]);
    unsigned long long myword = 0;  // lane j holds row (i0+j)'s bits [j0..j0+64)
#pragma unroll
    for (int mt = 0; mt < 4; ++mt)
#pragma unroll
      for (int rr = 0; rr < 4; ++rr) {
        unsigned long long b0 = __ballot(fabsf(acc[mt][0][rr]) >= eps);
        unsigned long long b1 = __ballot(fabsf(acc[mt][1][rr]) >= eps);
        unsigned long long b2 = __ballot(fabsf(acc[mt][2][rr]) >= eps);
        unsigned long long b3 = __ballot(fabsf(acc[mt][3][rr]) >= eps);
        if ((lane >> 4) == mt && (lane & 3) == rr) {
          int gj = (lane >> 2) & 3;
          myword = ((b0 >> (16 * gj)) & 0xFFFFull) |
                   (((b1 >> (16 * gj)) & 0xFFFFull) << 16) |
                   (((b2 >> (16 * gj)) & 0xFFFFull) << 32) |
                   (((b3 >> (16 * gj)) & 0xFFFFull) << 48);
        }
      }
    Awords[(size_t)(i0 + lane) * 128 + (j0 >> 6)] = myword;
    AT[(size_t)(j0 >> 6) * 8192 + i0 + lane] = myword;
    if (!diag) {  // mirrored tile via 64x64 bit transpose (ballot per column)
      unsigned long long tw = 0;
#pragma unroll
      for (int c2 = 0; c2 < 64; ++c2) {
        unsigned long long bc = __ballot((myword >> c2) & 1ull);
        if (lane == c2) tw = bc;
      }
      Awords[(size_t)(j0 + lane) * 128 + (i0 >> 6)] = tw;
      AT[(size_t)(i0 >> 6) * 8192 + j0 + lane] = tw;
    }
  }
}

// ---------------- histogram selection scan ----------------
template <int NB, int MODE>
__global__ __launch_bounds__(256) void scan_kernel(const unsigned int* __restrict__ hist,
                                                   unsigned int* __restrict__ sel) {
  __shared__ unsigned long long csum[256];
  const int t = threadIdx.x;
  const int PER = NB / 256;
  unsigned int vals[NB / 256];
  unsigned long long s = 0;
  for (int i = 0; i < PER; ++i) {
    unsigned v = 0;
    if (MODE == 0) {
      for (int cc = 0; cc < NHC; ++cc) v += hist[cc * NB + t * PER + i];
    } else {
      v = hist[t * PER + i];
    }
    vals[i] = v;
    s += v;
  }
  csum[t] = s;
  __syncthreads();
  for (int o = 1; o < 256; o <<= 1) {
    unsigned long long prev = (t >= o) ? csum[t - o] : 0ull;
    __syncthreads();
    csum[t] += prev;
    __syncthreads();
  }
  unsigned long long K = (MODE == 0) ? 63753421ull : (unsigned long long)sel[1];
  unsigned long long inc = csum[t], exc = inc - s;
  if (K > exc && K <= inc) {
    unsigned long long c = exc;
    for (int i = 0; i < PER; ++i) {
      c += vals[i];
      if (c >= K) {
        if (MODE == 0) {
          sel[0] = (unsigned)(t * PER + i);
          sel[1] = (unsigned)(K - (c - vals[i]));
        } else {
          float eps = ((float)sel[0] + (float)(t * PER + i) * (1.0f / 8192.0f)) *
                      (1.0f / 4096.0f);
          sel[2] = __float_as_uint(eps);
        }
        break;
      }
    }
  }
}

// ---------------- degree ----------------
__global__ __launch_bounds__(256) void deg_kernel(const unsigned long long* __restrict__ Awords,
                                                  float* __restrict__ deg_inv) {
  int row = blockIdx.x * 4 + (threadIdx.x >> 6);
  int lane = threadIdx.x & 63;
  int c = __popcll(Awords[row * 128 + lane]) + __popcll(Awords[row * 128 + 64 + lane]);
  for (int o = 32; o; o >>= 1) c += __shfl_down(c, o);
  if (lane == 0) deg_inv[row] = 1.0f / (float)max(c, 1);
}

// ---------------- lin: F-layout GEMM ----------------------------------------
// WBF8: write fp8 B-layout (hBF8) for aggA consumption.
template <bool TWO, bool RELU, bool RES, bool WF, bool WBF8, bool WRM>
__global__ __launch_bounds__(256) void lin_kernel(
    const short* __restrict__ A1, const short* __restrict__ B1, int K1,
    const short* __restrict__ A2, const short* __restrict__ B2, int K2,
    const float* __restrict__ bias, const short* __restrict__ resF,
    short* __restrict__ outF, unsigned char* __restrict__ outBF8,
    short* __restrict__ outRM) {
  const int i0 = blockIdx.x * 64, n0 = blockIdx.y * 64;
  const int tid = threadIdx.x, w = tid >> 6, lane = tid & 63;
  const int wy = (w >> 1) * 32, wx = (w & 1) * 32;
  f4v acc[2][2];
#pragma unroll
  for (int a = 0; a < 2; ++a)
#pragma unroll
    for (int b = 0; b < 2; ++b) acc[a][b] = (f4v){0.f, 0.f, 0.f, 0.f};

  const int ka = K1 >> 5;
  const int ra0 = (i0 + wy) >> 4, rb0 = (n0 + wx) >> 4;
  for (int cc = 0; cc < ka; ++cc) {
    s8v a0 = *(const s8v*)(A1 + ((ra0 + 0) * ka + cc) * 512 + lane * 8);
    s8v a1 = *(const s8v*)(A1 + ((ra0 + 1) * ka + cc) * 512 + lane * 8);
    s8v b0 = *(const s8v*)(B1 + ((rb0 + 0) * ka + cc) * 512 + lane * 8);
    s8v b1 = *(const s8v*)(B1 + ((rb0 + 1) * ka + cc) * 512 + lane * 8);
    acc[0][0] = MFMA(a0, b0, acc[0][0]);
    acc[0][1] = MFMA(a0, b1, acc[0][1]);
    acc[1][0] = MFMA(a1, b0, acc[1][0]);
    acc[1][1] = MFMA(a1, b1, acc[1][1]);
  }
  if constexpr (TWO) {
    const int kb = K2 >> 5;
    for (int cc = 0; cc < kb; ++cc) {
      s8v a0 = *(const s8v*)(A2 + ((ra0 + 0) * kb + cc) * 512 + lane * 8);
      s8v a1 = *(const s8v*)(A2 + ((ra0 + 1) * kb + cc) * 512 + lane * 8);
      s8v b0 = *(const s8v*)(B2 + ((rb0 + 0) * kb + cc) * 512 + lane * 8);
      s8v b1 = *(const s8v*)(B2 + ((rb0 + 1) * kb + cc) * 512 + lane * 8);
      acc[0][0] = MFMA(a0, b0, acc[0][0]);
      acc[0][1] = MFMA(a0, b1, acc[0][1]);
      acc[1][0] = MFMA(a1, b0, acc[1][0]);
      acc[1][1] = MFMA(a1, b1, acc[1][1]);
    }
  }
#pragma unroll
  for (int mt = 0; mt < 2; ++mt)
#pragma unroll
    for (int nt = 0; nt < 2; ++nt)
#pragma unroll
      for (int rr = 0; rr < 4; ++rr) {
        int row = i0 + wy + mt * 16 + (lane >> 4) * 4 + rr;
        int col = n0 + wx + nt * 16 + (lane & 15);
        float v = acc[mt][nt][rr] + bias[col];
        if constexpr (RES) {
          v += bf2f(resF[(size_t)((row >> 4) * 8 + (col >> 5)) * 512 +
                         (((col >> 3) & 3) * 16 + (row & 15)) * 8 + (col & 7)]);
        }
        if constexpr (RELU) v = fmaxf(v, 0.f);
        short sv = f2bf(v);
        if constexpr (WRM) outRM[row * 256 + col] = sv;
        if constexpr (WF) {
          outF[(size_t)((row >> 4) * 8 + (col >> 5)) * 512 +
               (((col >> 3) & 3) * 16 + (row & 15)) * 8 + (col & 7)] = sv;
        }
        if constexpr (WBF8) {
          outBF8[(size_t)((col >> 4) * 256 + (row >> 5)) * 512 +
                 (((row >> 3) & 3) * 16 + (col & 15)) * 8 + (row & 7)] = f2e4m3(v);
        }
      }
}

// ---------------- aggA: fp8 MFMA; partialF[z] = Fmajor(A @ h) ----------------
__global__ __launch_bounds__(256, 3) void aggA_kernel(
    const unsigned long long* __restrict__ AT, const unsigned char* __restrict__ hBF8,
    short* __restrict__ partial, int ksplit) {
  const int i0 = blockIdx.x * 128;
  const int f0 = blockIdx.y * 128;
  const int k0 = blockIdx.z * ksplit;
  const int tid = threadIdx.x, w = tid >> 6, lane = tid & 63;
  const int wy = (w >> 1) * 64, wx = f0 + (w & 1) * 64;
  const int lr = lane & 15, g = lane >> 4, g8 = g * 8;

  f4v acc[4][4];
#pragma unroll
  for (int a = 0; a < 4; ++a)
#pragma unroll
    for (int b = 0; b < 4; ++b) acc[a][b] = (f4v){0.f, 0.f, 0.f, 0.f};

  const unsigned long long* awp = AT + (size_t)(k0 >> 6) * 8192 + i0 + wy + lr;
  // fp8 chunks: 512 B each; chunk = (feat>>4)*256 + (node>>5)
  const unsigned char* bp0 = hBF8 + ((size_t)(wx >> 4) * 256 + (k0 >> 5)) * 512 + lane * 8;
  const unsigned char* bp1 = bp0 + 131072;   // +256 chunks * 512 B
  const unsigned char* bp2 = bp0 + 262144;
  const unsigned char* bp3 = bp0 + 393216;

  for (int kb = 0; kb < ksplit; kb += 64) {
    unsigned long long aw[4];
#pragma unroll
    for (int mt = 0; mt < 4; ++mt) aw[mt] = awp[mt * 16];
#pragma unroll
    for (int kc = 0; kc < 2; ++kc) {
      i64t bf[4];
      bf[0] = *(const i64t*)(bp0 + kc * 512);
      bf[1] = *(const i64t*)(bp1 + kc * 512);
      bf[2] = *(const i64t*)(bp2 + kc * 512);
      bf[3] = *(const i64t*)(bp3 + kc * 512);
#pragma unroll
      for (int mt = 0; mt < 4; ++mt) {
        unsigned byte = (unsigned)(aw[mt] >> (kc * 32 + g8)) & 0xFFu;
        unsigned lo4 = byte & 0xFu, hi4 = byte >> 4;
        unsigned d0 = ((lo4 & 1u) | ((lo4 & 2u) << 7) | ((lo4 & 4u) << 14) |
                       ((lo4 & 8u) << 21)) * 0x38u;
        unsigned d1 = ((hi4 & 1u) | ((hi4 & 2u) << 7) | ((hi4 & 4u) << 14) |
                       ((hi4 & 8u) << 21)) * 0x38u;
        i64t a = (i64t)(((unsigned long long)d1 << 32) | d0);
#pragma unroll
        for (int nt = 0; nt < 4; ++nt) acc[mt][nt] = MFMA8(a, bf[nt], acc[mt][nt]);
      }
    }
    awp += 8192;
    bp0 += 1024; bp1 += 1024; bp2 += 1024; bp3 += 1024;
  }
  short* P = partial + (size_t)blockIdx.z * 2097152;
#pragma unroll
  for (int mt = 0; mt < 4; ++mt)
#pragma unroll
    for (int nt = 0; nt < 4; ++nt)
#pragma unroll
      for (int rr = 0; rr < 4; ++rr) {
        int row = i0 + wy + mt * 16 + g * 4 + rr;
        int col = wx + nt * 16 + lr;
        P[(size_t)((row >> 4) * 8 + (col >> 5)) * 512 +
          (((col >> 3) & 3) * 16 + (row & 15)) * 8 + (col & 7)] = f2bf(acc[mt][nt][rr]);
      }
}

// combine: aggF = bf16((sum_z partialF[z]) * deg_inv[row]); A-layout in+out
__global__ __launch_bounds__(256) void combine_kernel(const short* __restrict__ p, int nsplit,
                                                      const float* __restrict__ deg_inv,
                                                      short* __restrict__ aggF) {
  int idx8 = blockIdx.x * 256 + threadIdx.x;  // one s8v group in A-layout
  float s[8];
#pragma unroll
  for (int e = 0; e < 8; ++e) s[e] = 0.f;
  for (int k = 0; k < nsplit; ++k) {
    s8v v = *(const s8v*)(p + (size_t)k * 2097152 + (size_t)idx8 * 8);
#pragma unroll
    for (int e = 0; e < 8; ++e) s[e] += bf2f(v[e]);
  }
  int chunk = idx8 >> 6, lane = idx8 & 63;
  int row = (chunk >> 3) * 16 + (lane & 15);
  float di = deg_inv[row];
  s8v o;
#pragma unroll
  for (int e = 0; e < 8; ++e) o[e] = f2bf(s[e] * di);
  *(s8v*)(aggF + (size_t)idx8 * 8) = o;
}

// ---------------- tail ----------------
__global__ __launch_bounds__(256) void vec3_kernel(const short* __restrict__ h2,
                                                   const float* __restrict__ o1wl,
                                                   const float* __restrict__ o1wr,
                                                   const float* __restrict__ oscw,
                                                   const float* __restrict__ oscb,
                                                   float* __restrict__ u, float* __restrict__ v,
                                                   float* __restrict__ sc) {
  int row = blockIdx.x * 4 + (threadIdx.x >> 6);
  int lane = threadIdx.x & 63;
  float su = 0.f, sv = 0.f, ss = 0.f;
#pragma unroll
  for (int e = 0; e < 4; ++e) {
    int k = lane * 4 + e;
    float hv = bf2f(h2[row * 256 + k]);
    su += hv * o1wl[k];
    sv += hv * o1wr[k];
    ss += hv * oscw[k];
  }
  for (int o = 1; o < 64; o <<= 1) {
    su += __shfl_xor(su, o);
    sv += __shfl_xor(sv, o);
    ss += __shfl_xor(ss, o);
  }
  if (lane == 0) {
    u[row] = su;
    v[row] = sv;
    sc[row] = ss + oscb[0];
  }
}

__global__ __launch_bounds__(256) void aggv1_kernel(const unsigned long long* __restrict__ Awords,
                                                    const float* __restrict__ u,
                                                    const float* __restrict__ deg_inv,
                                                    const float* __restrict__ v,
                                                    const float* __restrict__ o1bl,
                                                    float* __restrict__ o1) {
  int row = blockIdx.x * 4 + (threadIdx.x >> 6);
  int lane = threadIdx.x & 63;
  float s = 0.f;
#pragma unroll
  for (int wi = 0; wi < 2; ++wi) {
    unsigned long long bits = Awords[row * 128 + wi * 64 + lane];
    int base = (wi * 64 + lane) * 64;
    while (bits) {
      int b = __ffsll(bits) - 1;
      s += u[base + b];
      bits &= bits - 1;
    }
  }
  for (int o = 1; o < 64; o <<= 1) s += __shfl_xor(s, o);
  if (lane == 0) o1[row] = fmaxf(s * deg_inv[row] + o1bl[0] + v[row], 0.f);
}

__global__ __launch_bounds__(256) void aggv2_kernel(const unsigned long long* __restrict__ Awords,
                                                    const float* __restrict__ o1,
                                                    const float* __restrict__ deg_inv,
                                                    const float* __restrict__ o2wl,
                                                    const float* __restrict__ o2bl,
                                                    const float* __restrict__ o2wr,
                                                    const float* __restrict__ sc,
                                                    float* __restrict__ out) {
  int row = blockIdx.x * 4 + (threadIdx.x >> 6);
  int lane = threadIdx.x & 63;
  float s = 0.f;
#pragma unroll
  for (int wi = 0; wi < 2; ++wi) {
    unsigned long long bits = Awords[row * 128 + wi * 64 + lane];
    int base = (wi * 64 + lane) * 64;
    while (bits) {
      int b = __ffsll(bits) - 1;
      s += o1[base + b];
      bits &= bits - 1;
    }
  }
  for (int o = 1; o < 64; o <<= 1) s += __shfl_xor(s, o);
  if (lane == 0) {
    float z = s * deg_inv[row] * o2wl[0] + o2bl[0] + o1[row] * o2wr[0] + sc[row];
    out[row] = 1.f / (1.f + expf(-z));
  }
}

// ---------------- launch ----------------
extern "C" void kernel_launch(void* const* d_in, const int* in_sizes, int n_in,
                              void* d_out, int out_size, void* d_ws, size_t ws_size,
                              hipStream_t stream) {
  (void)in_sizes; (void)n_in; (void)out_size;
  const float* x     = (const float*)d_in[0];
  const float* w_in  = (const float*)d_in[1];
  const float* b_in  = (const float*)d_in[2];
  const float* h1_wl = (const float*)d_in[3];
  const float* h1_bl = (const float*)d_in[4];
  const float* h1_wr = (const float*)d_in[5];
  const float* h2_wl = (const float*)d_in[6];
  const float* h2_bl = (const float*)d_in[7];
  const float* h2_wr = (const float*)d_in[8];
  const float* o1_wl = (const float*)d_in[9];
  const float* o1_bl = (const float*)d_in[10];
  const float* o1_wr = (const float*)d_in[11];
  const float* o2_wl = (const float*)d_in[12];
  const float* o2_bl = (const float*)d_in[13];
  const float* o2_wr = (const float*)d_in[14];
  const float* osc_w = (const float*)d_in[15];
  const float* osc_b = (const float*)d_in[16];
  float* out = (float*)d_out;

  char* ws = (char*)d_ws;
  size_t off = 0;
  auto alloc = [&](size_t bytes) -> char* {
    char* p = ws + off;
    off += (bytes + 255) & ~(size_t)255;
    return p;
  };
  short* xnF   = (short*)alloc(8192 * 128 * 2);
  short* xbF   = (short*)alloc(8192 * 128 * 2);
  short* w_inF = (short*)alloc(256 * 128 * 2);
  short* w1lF  = (short*)alloc(256 * 256 * 2);
  short* w1rF  = (short*)alloc(256 * 256 * 2);
  short* w2lF  = (short*)alloc(256 * 256 * 2);
  short* w2rF  = (short*)alloc(256 * 256 * 2);
  unsigned int* hist1 = (unsigned int*)alloc(NHC * 4096 * 4);
  unsigned int* hist2 = (unsigned int*)alloc(8192 * 4);
  unsigned int* sel   = (unsigned int*)alloc(256);
  float* deg_inv = (float*)alloc(8192 * 4);
  float* ubuf  = (float*)alloc(8192 * 4);
  float* vbuf  = (float*)alloc(8192 * 4);
  float* scbuf = (float*)alloc(8192 * 4);
  float* o1buf = (float*)alloc(8192 * 4);
  unsigned long long* Awords = (unsigned long long*)alloc((size_t)8192 * 128 * 8);
  unsigned long long* AT     = (unsigned long long*)alloc((size_t)8192 * 128 * 8);
  short* h0F  = (short*)alloc((size_t)8192 * 256 * 2);
  unsigned char* h0BF8 = (unsigned char*)alloc((size_t)8192 * 256);
  short* h1F  = (short*)alloc((size_t)8192 * 256 * 2);
  unsigned char* h1BF8 = (unsigned char*)alloc((size_t)8192 * 256);
  short* h2   = (short*)alloc((size_t)8192 * 256 * 2);
  short* aggF = (short*)alloc((size_t)8192 * 256 * 2);
  const size_t SLICE = (size_t)8192 * 256 * 2;
  int nsplit = (ws_size >= off + 8 * SLICE + 4096) ? 8
             : (ws_size >= off + 4 * SLICE + 4096) ? 4 : 2;
  short* partials = (short*)alloc((size_t)nsplit * SLICE);
  const int ksplit = 8192 / nsplit;

  hipMemsetAsync(hist1, 0, (NHC * 4096 + 8192) * 4, stream);
  prep_kernel<<<1280, 256, 0, stream>>>(x, w_in, h1_wl, h1_wr, h2_wl, h2_wr,
                                        xbF, xnF, w_inF, w1lF, w1rF, w2lF, w2rF);
  hist0_kernel<<<688, 256, 0, stream>>>(xnF, hist1);
  scan_kernel<4096, 0><<<1, 256, 0, stream>>>(hist1, sel);
  sim_kernel<1><<<NTRI / 4, 256, 0, stream>>>(xnF, hist2, sel, nullptr, nullptr);
  scan_kernel<8192, 1><<<1, 256, 0, stream>>>(hist2, sel);
  sim_kernel<2><<<NTRI / 4, 256, 0, stream>>>(xnF, nullptr, sel, Awords, AT);
  deg_kernel<<<2048, 256, 0, stream>>>(Awords, deg_inv);

  // h0 = relu(x @ w_in + b_in)  -> h0F (A-layout) + h0BF8 (fp8 B-layout)
  lin_kernel<false, true, false, true, true, false>
      <<<dim3(128, 4), 256, 0, stream>>>(xbF, w_inF, 128, nullptr, nullptr, 0,
                                         b_in, nullptr, h0F, h0BF8, nullptr);
  // h1 = relu(agg(h0)@h1_wl + h1_bl + h0@h1_wr)  -> h1F + h1BF8
  aggA_kernel<<<dim3(64, 2, nsplit), 256, 0, stream>>>(AT, h0BF8, partials, ksplit);
  combine_kernel<<<1024, 256, 0, stream>>>(partials, nsplit, deg_inv, aggF);
  lin_kernel<true, true, false, true, true, false>
      <<<dim3(128, 4), 256, 0, stream>>>(aggF, w1lF, 256, h0F, w1rF, 256,
                                         h1_bl, nullptr, h1F, h1BF8, nullptr);
  // h2 = relu(agg(h1)@h2_wl + h2_bl + h1@h2_wr + h0)  -> h2 row-major
  aggA_kernel<<<dim3(64, 2, nsplit), 256, 0, stream>>>(AT, h1BF8, partials, ksplit);
  combine_kernel<<<1024, 256, 0, stream>>>(partials, nsplit, deg_inv, aggF);
  lin_kernel<true, true, true, false, false, true>
      <<<dim3(128, 4), 256, 0, stream>>>(aggF, w2lF, 256, h1F, w2rF, 256,
                                         h2_bl, h0F, nullptr, nullptr, h2);
  // output block
  vec3_kernel<<<2048, 256, 0, stream>>>(h2, o1_wl, o1_wr, osc_w, osc_b, ubuf, vbuf, scbuf);
  aggv1_kernel<<<2048, 256, 0, stream>>>(Awords, ubuf, deg_inv, vbuf, o1_bl, o1buf);
  aggv2_kernel<<<2048, 256, 0, stream>>>(Awords, o1buf, deg_inv, o2_wl, o2_bl, o2_wr, scbuf, out);
}

// Round 17
// 289.183 us; speedup vs baseline: 1.6169x; 1.0345x over previous
//
#include <hip/hip_runtime.h>

// GNN_79937931313503: dynamic-graph SAGE GNN on MI355X.
// R17: aggA magic-mul bit->fp8 expansion (3 ops/dword vs 11) + occupancy 4
// waves/SIMD (acc64+vgpr~56 fits 128/wave budget). Rest = R16.

typedef __attribute__((ext_vector_type(8))) short s8v;   // 8 x bf16 (4 VGPR)
typedef __attribute__((ext_vector_type(4))) float f4v;   // MFMA C/D frag
typedef long long i64t;                                  // fp8 MFMA operand

__device__ __forceinline__ f4v MFMA(s8v a, s8v b, f4v c) {
  return __builtin_amdgcn_mfma_f32_16x16x32_bf16(a, b, c, 0, 0, 0);
}
__device__ __forceinline__ f4v MFMA8(i64t a, i64t b, f4v c) {
  return __builtin_amdgcn_mfma_f32_16x16x32_fp8_fp8(a, b, c, 0, 0, 0);
}
__device__ __forceinline__ short f2bf(float f) {  // RNE float->bf16 bits
  unsigned u = __float_as_uint(f);
  return (short)((u + 0x7FFFu + ((u >> 16) & 1u)) >> 16);
}
__device__ __forceinline__ float bf2f(short s) {
  return __uint_as_float(((unsigned)(unsigned short)s) << 16);
}
// RNE float -> OCP e4m3fn byte
__device__ __forceinline__ unsigned char f2e4m3(float f) {
  unsigned u = __float_as_uint(f);
  unsigned sign = (u >> 24) & 0x80u;
  unsigned a = u & 0x7FFFFFFFu;
  if (a >= 0x43E00000u) return (unsigned char)(sign | 0x7Eu);  // clamp 448
  if (a < 0x3C800000u) {  // below 2^-6: denormal units of 2^-9
    unsigned n = (unsigned)rintf(__uint_as_float(a) * 512.0f);
    return (unsigned char)(sign | n);
  }
  unsigned r = a + 0x7FFFFu + ((a >> 20) & 1u);
  unsigned bits = (r >> 20) - 960u;
  if (bits > 0x7Eu) bits = 0x7Eu;
  return (unsigned char)(sign | bits);
}

#define NT64 128
#define NTRI 8256  // 128*129/2
#define NHC 8      // global histogram copies

__device__ __forceinline__ void tri_invert(int t, int& r, int& c) {
  int rr = (int)((257.0f - sqrtf((float)(257 * 257 - 8 * t))) * 0.5f);
  if (rr < 0) rr = 0;
  if (rr > 127) rr = 127;
  while (rr < 127 && ((rr + 1) * NT64 - (rr + 1) * rr / 2) <= t) ++rr;
  while (rr > 0 && (rr * NT64 - rr * (rr - 1) / 2) > t) --rr;
  r = rr;
  c = rr + (t - (rr * NT64 - rr * (rr - 1) / 2));
}

// ---------------- prep: x (blocks 0..127) + weights (blocks 128..1279) ------
__global__ __launch_bounds__(256) void prep_kernel(
    const float* __restrict__ x, const float* __restrict__ w_in,
    const float* __restrict__ w1l, const float* __restrict__ w1r,
    const float* __restrict__ w2l, const float* __restrict__ w2r,
    short* __restrict__ xbF, short* __restrict__ xnF, short* __restrict__ w_inF,
    short* __restrict__ w1lF, short* __restrict__ w1rF,
    short* __restrict__ w2lF, short* __restrict__ w2rF) {
  if (blockIdx.x < 128) {
    const int w = threadIdx.x >> 6, lane = threadIdx.x & 63;
    const int rg = blockIdx.x * 4 + w;
    const int m = lane & 15, g = lane >> 4;
    const int row = rg * 16 + m;
    float v[4][8];
    float ss = 0.f;
#pragma unroll
    for (int kc = 0; kc < 4; ++kc) {
      const float* src = x + row * 128 + kc * 32 + g * 8;
      float4 a = *(const float4*)src;
      float4 b = *(const float4*)(src + 4);
      v[kc][0] = a.x; v[kc][1] = a.y; v[kc][2] = a.z; v[kc][3] = a.w;
      v[kc][4] = b.x; v[kc][5] = b.y; v[kc][6] = b.z; v[kc][7] = b.w;
#pragma unroll
      for (int e = 0; e < 8; ++e) ss += v[kc][e] * v[kc][e];
    }
    ss += __shfl_xor(ss, 16);
    ss += __shfl_xor(ss, 32);
    float inv = 1.0f / fmaxf(sqrtf(ss), 1e-8f);
#pragma unroll
    for (int kc = 0; kc < 4; ++kc) {
      s8v raw, nrm;
#pragma unroll
      for (int e = 0; e < 8; ++e) {
        raw[e] = f2bf(v[kc][e]);
        nrm[e] = f2bf(v[kc][e] * inv);
      }
      *(s8v*)(xbF + (rg * 4 + kc) * 512 + lane * 8) = raw;
      *(s8v*)(xnF + (rg * 4 + kc) * 512 + lane * 8) = nrm;
    }
    return;
  }
  int idx = (blockIdx.x - 128) * 256 + threadIdx.x;
  if (idx >= 294912) return;
  if (idx < 32768) {                       // w_in [128k][256n], K=128
    int n = idx >> 7, k = idx & 127;
    size_t pos = (size_t)((n >> 4) * 4 + (k >> 5)) * 512 +
                 (((k >> 3) & 3) * 16 + (n & 15)) * 8 + (k & 7);
    w_inF[pos] = f2bf(w_in[k * 256 + n]);
  } else {
    int j = idx - 32768;
    int m = j >> 16, r = j & 65535;
    int n = r >> 8, k = r & 255;
    const float* src = (m == 0) ? w1l : (m == 1) ? w1r : (m == 2) ? w2l : w2r;
    short* dst = (m == 0) ? w1lF : (m == 1) ? w1rF : (m == 2) ? w2lF : w2rF;
    size_t pos = (size_t)((n >> 4) * 8 + (k >> 5)) * 512 +
                 (((k >> 3) & 3) * 16 + (n & 15)) * 8 + (k & 7);
    dst[pos] = f2bf(src[k * 256 + n]);
  }
}

// ---------------- hist0: persistent grid-stride linear histogram ----------
__global__ __launch_bounds__(256) void hist0_kernel(const short* __restrict__ xnF,
                                                    unsigned int* __restrict__ hist) {
  __shared__ unsigned int lh[4096];
  const int tid = threadIdx.x, w = tid >> 6, lane = tid & 63;
  for (int b = tid; b < 4096; b += 256) lh[b] = 0;
  __syncthreads();

  for (int tg = blockIdx.x; tg < NTRI / 4; tg += gridDim.x) {
    int t = tg * 4 + w;
    int r, c;
    tri_invert(t, r, c);
    const bool diag = (r == c);
    f4v acc[4][4];
#pragma unroll
    for (int a = 0; a < 4; ++a)
#pragma unroll
      for (int b = 0; b < 4; ++b) acc[a][b] = (f4v){0.f, 0.f, 0.f, 0.f};
    const int rga = r * 4, rgb = c * 4;
#pragma unroll
    for (int kc = 0; kc < 4; ++kc) {
      s8v af[4], bf[4];
#pragma unroll
      for (int mt = 0; mt < 4; ++mt)
        af[mt] = *(const s8v*)(xnF + ((rga + mt) * 4 + kc) * 512 + lane * 8);
#pragma unroll
      for (int nt = 0; nt < 4; ++nt)
        bf[nt] = *(const s8v*)(xnF + ((rgb + nt) * 4 + kc) * 512 + lane * 8);
#pragma unroll
      for (int mt = 0; mt < 4; ++mt)
#pragma unroll
        for (int nt = 0; nt < 4; ++nt) acc[mt][nt] = MFMA(af[mt], bf[nt], acc[mt][nt]);
    }
    unsigned wgt = diag ? 1u : 2u;
#pragma unroll
    for (int mt = 0; mt < 4; ++mt)
      for (int nt = 0; nt < 4; ++nt)
        for (int rr = 0; rr < 4; ++rr) {
          float val = fabsf(acc[mt][nt][rr]);
          int bin = (int)(val * 4096.0f);
          bin = min(max(bin, 0), 4095);
          atomicAdd(&lh[bin], wgt);
        }
  }
  __syncthreads();
  unsigned int* hc = hist + (blockIdx.x & (NHC - 1)) * 4096;
  for (int b = tid; b < 4096; b += 256)
    if (lh[b]) atomicAdd(&hc[b], lh[b]);
}

// ---------------- sim: per-wave 64x64 tiles, upper triangle only ----------------
template <int MODE>
__global__ __launch_bounds__(256) void sim_kernel(
    const short* __restrict__ xnF, unsigned int* __restrict__ hist,
    unsigned int* __restrict__ sel, unsigned long long* __restrict__ Awords,
    unsigned long long* __restrict__ AT) {
  const int tid = threadIdx.x, w = tid >> 6, lane = tid & 63;
  int t = blockIdx.x * 4 + w;
  int r, c;
  tri_invert(t, r, c);
  const int i0 = r * 64, j0 = c * 64;
  const bool diag = (r == c);

  f4v acc[4][4];
#pragma unroll
  for (int a = 0; a < 4; ++a)
#pragma unroll
    for (int b = 0; b < 4; ++b) acc[a][b] = (f4v){0.f, 0.f, 0.f, 0.f};

  const int rga = r * 4, rgb = c * 4;
#pragma unroll
  for (int kc = 0; kc < 4; ++kc) {
    s8v af[4], bf[4];
#pragma unroll
    for (int mt = 0; mt < 4; ++mt)
      af[mt] = *(const s8v*)(xnF + ((rga + mt) * 4 + kc) * 512 + lane * 8);
#pragma unroll
    for (int nt = 0; nt < 4; ++nt)
      bf[nt] = *(const s8v*)(xnF + ((rgb + nt) * 4 + kc) * 512 + lane * 8);
#pragma unroll
    for (int mt = 0; mt < 4; ++mt)
#pragma unroll
      for (int nt = 0; nt < 4; ++nt) acc[mt][nt] = MFMA(af[mt], bf[nt], acc[mt][nt]);
  }

  if (MODE == 1) {
    int pref = (int)sel[0];
    unsigned wgt = diag ? 1u : 2u;
#pragma unroll
    for (int mt = 0; mt < 4; ++mt)
      for (int nt = 0; nt < 4; ++nt)
        for (int rr = 0; rr < 4; ++rr) {
          float tt = fabsf(acc[mt][nt][rr]) * 4096.0f;
          int bin = min(max((int)tt, 0), 4095);
          if (bin == pref) {
            int b2 = (int)((tt - (float)pref) * 8192.0f);
            b2 = min(max(b2, 0), 8191);
            atomicAdd(&hist[b2], wgt);
          }
        }
  } else {
    float eps = __uint_as_float(sel[2]);
    unsigned long long myword = 0;  // lane j holds row (i0+j)'s bits [j0..j0+64)
#pragma unroll
    for (int mt = 0; mt < 4; ++mt)
#pragma unroll
      for (int rr = 0; rr < 4; ++rr) {
        unsigned long long b0 = __ballot(fabsf(acc[mt][0][rr]) >= eps);
        unsigned long long b1 = __ballot(fabsf(acc[mt][1][rr]) >= eps);
        unsigned long long b2 = __ballot(fabsf(acc[mt][2][rr]) >= eps);
        unsigned long long b3 = __ballot(fabsf(acc[mt][3][rr]) >= eps);
        if ((lane >> 4) == mt && (lane & 3) == rr) {
          int gj = (lane >> 2) & 3;
          myword = ((b0 >> (16 * gj)) & 0xFFFFull) |
                   (((b1 >> (16 * gj)) & 0xFFFFull) << 16) |
                   (((b2 >> (16 * gj)) & 0xFFFFull) << 32) |
                   (((b3 >> (16 * gj)) & 0xFFFFull) << 48);
        }
      }
    Awords[(size_t)(i0 + lane) * 128 + (j0 >> 6)] = myword;
    AT[(size_t)(j0 >> 6) * 8192 + i0 + lane] = myword;
    if (!diag) {  // mirrored tile via 64x64 bit transpose (ballot per column)
      unsigned long long tw = 0;
#pragma unroll
      for (int c2 = 0; c2 < 64; ++c2) {
        unsigned long long bc = __ballot((myword >> c2) & 1ull);
        if (lane == c2) tw = bc;
      }
      Awords[(size_t)(j0 + lane) * 128 + (i0 >> 6)] = tw;
      AT[(size_t)(i0 >> 6) * 8192 + j0 + lane] = tw;
    }
  }
}

// ---------------- histogram selection scan ----------------
template <int NB, int MODE>
__global__ __launch_bounds__(256) void scan_kernel(const unsigned int* __restrict__ hist,
                                                   unsigned int* __restrict__ sel) {
  __shared__ unsigned long long csum[256];
  const int t = threadIdx.x;
  const int PER = NB / 256;
  unsigned int vals[NB / 256];
  unsigned long long s = 0;
  for (int i = 0; i < PER; ++i) {
    unsigned v = 0;
    if (MODE == 0) {
      for (int cc = 0; cc < NHC; ++cc) v += hist[cc * NB + t * PER + i];
    } else {
      v = hist[t * PER + i];
    }
    vals[i] = v;
    s += v;
  }
  csum[t] = s;
  __syncthreads();
  for (int o = 1; o < 256; o <<= 1) {
    unsigned long long prev = (t >= o) ? csum[t - o] : 0ull;
    __syncthreads();
    csum[t] += prev;
    __syncthreads();
  }
  unsigned long long K = (MODE == 0) ? 63753421ull : (unsigned long long)sel[1];
  unsigned long long inc = csum[t], exc = inc - s;
  if (K > exc && K <= inc) {
    unsigned long long c = exc;
    for (int i = 0; i < PER; ++i) {
      c += vals[i];
      if (c >= K) {
        if (MODE == 0) {
          sel[0] = (unsigned)(t * PER + i);
          sel[1] = (unsigned)(K - (c - vals[i]));
        } else {
          float eps = ((float)sel[0] + (float)(t * PER + i) * (1.0f / 8192.0f)) *
                      (1.0f / 4096.0f);
          sel[2] = __float_as_uint(eps);
        }
        break;
      }
    }
  }
}

// ---------------- degree ----------------
__global__ __launch_bounds__(256) void deg_kernel(const unsigned long long* __restrict__ Awords,
                                                  float* __restrict__ deg_inv) {
  int row = blockIdx.x * 4 + (threadIdx.x >> 6);
  int lane = threadIdx.x & 63;
  int c = __popcll(Awords[row * 128 + lane]) + __popcll(Awords[row * 128 + 64 + lane]);
  for (int o = 32; o; o >>= 1) c += __shfl_down(c, o);
  if (lane == 0) deg_inv[row] = 1.0f / (float)max(c, 1);
}

// ---------------- lin: F-layout GEMM ----------------------------------------
template <bool TWO, bool RELU, bool RES, bool WF, bool WBF8, bool WRM>
__global__ __launch_bounds__(256) void lin_kernel(
    const short* __restrict__ A1, const short* __restrict__ B1, int K1,
    const short* __restrict__ A2, const short* __restrict__ B2, int K2,
    const float* __restrict__ bias, const short* __restrict__ resF,
    short* __restrict__ outF, unsigned char* __restrict__ outBF8,
    short* __restrict__ outRM) {
  const int i0 = blockIdx.x * 64, n0 = blockIdx.y * 64;
  const int tid = threadIdx.x, w = tid >> 6, lane = tid & 63;
  const int wy = (w >> 1) * 32, wx = (w & 1) * 32;
  f4v acc[2][2];
#pragma unroll
  for (int a = 0; a < 2; ++a)
#pragma unroll
    for (int b = 0; b < 2; ++b) acc[a][b] = (f4v){0.f, 0.f, 0.f, 0.f};

  const int ka = K1 >> 5;
  const int ra0 = (i0 + wy) >> 4, rb0 = (n0 + wx) >> 4;
  for (int cc = 0; cc < ka; ++cc) {
    s8v a0 = *(const s8v*)(A1 + ((ra0 + 0) * ka + cc) * 512 + lane * 8);
    s8v a1 = *(const s8v*)(A1 + ((ra0 + 1) * ka + cc) * 512 + lane * 8);
    s8v b0 = *(const s8v*)(B1 + ((rb0 + 0) * ka + cc) * 512 + lane * 8);
    s8v b1 = *(const s8v*)(B1 + ((rb0 + 1) * ka + cc) * 512 + lane * 8);
    acc[0][0] = MFMA(a0, b0, acc[0][0]);
    acc[0][1] = MFMA(a0, b1, acc[0][1]);
    acc[1][0] = MFMA(a1, b0, acc[1][0]);
    acc[1][1] = MFMA(a1, b1, acc[1][1]);
  }
  if constexpr (TWO) {
    const int kb = K2 >> 5;
    for (int cc = 0; cc < kb; ++cc) {
      s8v a0 = *(const s8v*)(A2 + ((ra0 + 0) * kb + cc) * 512 + lane * 8);
      s8v a1 = *(const s8v*)(A2 + ((ra0 + 1) * kb + cc) * 512 + lane * 8);
      s8v b0 = *(const s8v*)(B2 + ((rb0 + 0) * kb + cc) * 512 + lane * 8);
      s8v b1 = *(const s8v*)(B2 + ((rb0 + 1) * kb + cc) * 512 + lane * 8);
      acc[0][0] = MFMA(a0, b0, acc[0][0]);
      acc[0][1] = MFMA(a0, b1, acc[0][1]);
      acc[1][0] = MFMA(a1, b0, acc[1][0]);
      acc[1][1] = MFMA(a1, b1, acc[1][1]);
    }
  }
#pragma unroll
  for (int mt = 0; mt < 2; ++mt)
#pragma unroll
    for (int nt = 0; nt < 2; ++nt)
#pragma unroll
      for (int rr = 0; rr < 4; ++rr) {
        int row = i0 + wy + mt * 16 + (lane >> 4) * 4 + rr;
        int col = n0 + wx + nt * 16 + (lane & 15);
        float v = acc[mt][nt][rr] + bias[col];
        if constexpr (RES) {
          v += bf2f(resF[(size_t)((row >> 4) * 8 + (col >> 5)) * 512 +
                         (((col >> 3) & 3) * 16 + (row & 15)) * 8 + (col & 7)]);
        }
        if constexpr (RELU) v = fmaxf(v, 0.f);
        short sv = f2bf(v);
        if constexpr (WRM) outRM[row * 256 + col] = sv;
        if constexpr (WF) {
          outF[(size_t)((row >> 4) * 8 + (col >> 5)) * 512 +
               (((col >> 3) & 3) * 16 + (row & 15)) * 8 + (col & 7)] = sv;
        }
        if constexpr (WBF8) {
          outBF8[(size_t)((col >> 4) * 256 + (row >> 5)) * 512 +
                 (((row >> 3) & 3) * 16 + (col & 15)) * 8 + (row & 7)] = f2e4m3(v);
        }
      }
}

// ---------------- aggA: fp8 MFMA; partialF[z] = Fmajor(A @ h) ----------------
// Magic-mul bit->fp8 spread: ((n4*0x00204081)&0x01010101)*0x38 (3 ops/dword).
__global__ __launch_bounds__(256, 4) void aggA_kernel(
    const unsigned long long* __restrict__ AT, const unsigned char* __restrict__ hBF8,
    short* __restrict__ partial, int ksplit) {
  const int i0 = blockIdx.x * 128;
  const int f0 = blockIdx.y * 128;
  const int k0 = blockIdx.z * ksplit;
  const int tid = threadIdx.x, w = tid >> 6, lane = tid & 63;
  const int wy = (w >> 1) * 64, wx = f0 + (w & 1) * 64;
  const int lr = lane & 15, g = lane >> 4, g8 = g * 8;

  f4v acc[4][4];
#pragma unroll
  for (int a = 0; a < 4; ++a)
#pragma unroll
    for (int b = 0; b < 4; ++b) acc[a][b] = (f4v){0.f, 0.f, 0.f, 0.f};

  const unsigned long long* awp = AT + (size_t)(k0 >> 6) * 8192 + i0 + wy + lr;
  const unsigned char* bp0 = hBF8 + ((size_t)(wx >> 4) * 256 + (k0 >> 5)) * 512 + lane * 8;
  const unsigned char* bp1 = bp0 + 131072;
  const unsigned char* bp2 = bp0 + 262144;
  const unsigned char* bp3 = bp0 + 393216;

  for (int kb = 0; kb < ksplit; kb += 64) {
    unsigned long long aw[4];
#pragma unroll
    for (int mt = 0; mt < 4; ++mt) aw[mt] = awp[mt * 16];
#pragma unroll
    for (int kc = 0; kc < 2; ++kc) {
      i64t bf[4];
      bf[0] = *(const i64t*)(bp0 + kc * 512);
      bf[1] = *(const i64t*)(bp1 + kc * 512);
      bf[2] = *(const i64t*)(bp2 + kc * 512);
      bf[3] = *(const i64t*)(bp3 + kc * 512);
#pragma unroll
      for (int mt = 0; mt < 4; ++mt) {
        unsigned byte = (unsigned)(aw[mt] >> (kc * 32 + g8)) & 0xFFu;
        unsigned d0 = (((byte & 0xFu) * 0x00204081u) & 0x01010101u) * 0x38u;
        unsigned d1 = (((byte >> 4) * 0x00204081u) & 0x01010101u) * 0x38u;
        i64t a = (i64t)(((unsigned long long)d1 << 32) | d0);
#pragma unroll
        for (int nt = 0; nt < 4; ++nt) acc[mt][nt] = MFMA8(a, bf[nt], acc[mt][nt]);
      }
    }
    awp += 8192;
    bp0 += 1024; bp1 += 1024; bp2 += 1024; bp3 += 1024;
  }
  short* P = partial + (size_t)blockIdx.z * 2097152;
#pragma unroll
  for (int mt = 0; mt < 4; ++mt)
#pragma unroll
    for (int nt = 0; nt < 4; ++nt)
#pragma unroll
      for (int rr = 0; rr < 4; ++rr) {
        int row = i0 + wy + mt * 16 + g * 4 + rr;
        int col = wx + nt * 16 + lr;
        P[(size_t)((row >> 4) * 8 + (col >> 5)) * 512 +
          (((col >> 3) & 3) * 16 + (row & 15)) * 8 + (col & 7)] = f2bf(acc[mt][nt][rr]);
      }
}

// combine: aggF = bf16((sum_z partialF[z]) * deg_inv[row]); A-layout in+out
__global__ __launch_bounds__(256) void combine_kernel(const short* __restrict__ p, int nsplit,
                                                      const float* __restrict__ deg_inv,
                                                      short* __restrict__ aggF) {
  int idx8 = blockIdx.x * 256 + threadIdx.x;  // one s8v group in A-layout
  float s[8];
#pragma unroll
  for (int e = 0; e < 8; ++e) s[e] = 0.f;
  for (int k = 0; k < nsplit; ++k) {
    s8v v = *(const s8v*)(p + (size_t)k * 2097152 + (size_t)idx8 * 8);
#pragma unroll
    for (int e = 0; e < 8; ++e) s[e] += bf2f(v[e]);
  }
  int chunk = idx8 >> 6, lane = idx8 & 63;
  int row = (chunk >> 3) * 16 + (lane & 15);
  float di = deg_inv[row];
  s8v o;
#pragma unroll
  for (int e = 0; e < 8; ++e) o[e] = f2bf(s[e] * di);
  *(s8v*)(aggF + (size_t)idx8 * 8) = o;
}

// ---------------- tail ----------------
__global__ __launch_bounds__(256) void vec3_kernel(const short* __restrict__ h2,
                                                   const float* __restrict__ o1wl,
                                                   const float* __restrict__ o1wr,
                                                   const float* __restrict__ oscw,
                                                   const float* __restrict__ oscb,
                                                   float* __restrict__ u, float* __restrict__ v,
                                                   float* __restrict__ sc) {
  int row = blockIdx.x * 4 + (threadIdx.x >> 6);
  int lane = threadIdx.x & 63;
  float su = 0.f, sv = 0.f, ss = 0.f;
#pragma unroll
  for (int e = 0; e < 4; ++e) {
    int k = lane * 4 + e;
    float hv = bf2f(h2[row * 256 + k]);
    su += hv * o1wl[k];
    sv += hv * o1wr[k];
    ss += hv * oscw[k];
  }
  for (int o = 1; o < 64; o <<= 1) {
    su += __shfl_xor(su, o);
    sv += __shfl_xor(sv, o);
    ss += __shfl_xor(ss, o);
  }
  if (lane == 0) {
    u[row] = su;
    v[row] = sv;
    sc[row] = ss + oscb[0];
  }
}

__global__ __launch_bounds__(256) void aggv1_kernel(const unsigned long long* __restrict__ Awords,
                                                    const float* __restrict__ u,
                                                    const float* __restrict__ deg_inv,
                                                    const float* __restrict__ v,
                                                    const float* __restrict__ o1bl,
                                                    float* __restrict__ o1) {
  int row = blockIdx.x * 4 + (threadIdx.x >> 6);
  int lane = threadIdx.x & 63;
  float s = 0.f;
#pragma unroll
  for (int wi = 0; wi < 2; ++wi) {
    unsigned long long bits = Awords[row * 128 + wi * 64 + lane];
    int base = (wi * 64 + lane) * 64;
    while (bits) {
      int b = __ffsll(bits) - 1;
      s += u[base + b];
      bits &= bits - 1;
    }
  }
  for (int o = 1; o < 64; o <<= 1) s += __shfl_xor(s, o);
  if (lane == 0) o1[row] = fmaxf(s * deg_inv[row] + o1bl[0] + v[row], 0.f);
}

__global__ __launch_bounds__(256) void aggv2_kernel(const unsigned long long* __restrict__ Awords,
                                                    const float* __restrict__ o1,
                                                    const float* __restrict__ deg_inv,
                                                    const float* __restrict__ o2wl,
                                                    const float* __restrict__ o2bl,
                                                    const float* __restrict__ o2wr,
                                                    const float* __restrict__ sc,
                                                    float* __restrict__ out) {
  int row = blockIdx.x * 4 + (threadIdx.x >> 6);
  int lane = threadIdx.x & 63;
  float s = 0.f;
#pragma unroll
  for (int wi = 0; wi < 2; ++wi) {
    unsigned long long bits = Awords[row * 128 + wi * 64 + lane];
    int base = (wi * 64 + lane) * 64;
    while (bits) {
      int b = __ffsll(bits) - 1;
      s += o1[base + b];
      bits &= bits - 1;
    }
  }
  for (int o = 1; o < 64; o <<= 1) s += __shfl_xor(s, o);
  if (lane == 0) {
    float z = s * deg_inv[row] * o2wl[0] + o2bl[0] + o1[row] * o2wr[0] + sc[row];
    out[row] = 1.f / (1.f + expf(-z));
  }
}

// ---------------- launch ----------------
extern "C" void kernel_launch(void* const* d_in, const int* in_sizes, int n_in,
                              void* d_out, int out_size, void* d_ws, size_t ws_size,
                              hipStream_t stream) {
  (void)in_sizes; (void)n_in; (void)out_size;
  const float* x     = (const float*)d_in[0];
  const float* w_in  = (const float*)d_in[1];
  const float* b_in  = (const float*)d_in[2];
  const float* h1_wl = (const float*)d_in[3];
  const float* h1_bl = (const float*)d_in[4];
  const float* h1_wr = (const float*)d_in[5];
  const float* h2_wl = (const float*)d_in[6];
  const float* h2_bl = (const float*)d_in[7];
  const float* h2_wr = (const float*)d_in[8];
  const float* o1_wl = (const float*)d_in[9];
  const float* o1_bl = (const float*)d_in[10];
  const float* o1_wr = (const float*)d_in[11];
  const float* o2_wl = (const float*)d_in[12];
  const float* o2_bl = (const float*)d_in[13];
  const float* o2_wr = (const float*)d_in[14];
  const float* osc_w = (const float*)d_in[15];
  const float* osc_b = (const float*)d_in[16];
  float* out = (float*)d_out;

  char* ws = (char*)d_ws;
  size_t off = 0;
  auto alloc = [&](size_t bytes) -> char* {
    char* p = ws + off;
    off += (bytes + 255) & ~(size_t)255;
    return p;
  };
  short* xnF   = (short*)alloc(8192 * 128 * 2);
  short* xbF   = (short*)alloc(8192 * 128 * 2);
  short* w_inF = (short*)alloc(256 * 128 * 2);
  short* w1lF  = (short*)alloc(256 * 256 * 2);
  short* w1rF  = (short*)alloc(256 * 256 * 2);
  short* w2lF  = (short*)alloc(256 * 256 * 2);
  short* w2rF  = (short*)alloc(256 * 256 * 2);
  unsigned int* hist1 = (unsigned int*)alloc(NHC * 4096 * 4);
  unsigned int* hist2 = (unsigned int*)alloc(8192 * 4);
  unsigned int* sel   = (unsigned int*)alloc(256);
  float* deg_inv = (float*)alloc(8192 * 4);
  float* ubuf  = (float*)alloc(8192 * 4);
  float* vbuf  = (float*)alloc(8192 * 4);
  float* scbuf = (float*)alloc(8192 * 4);
  float* o1buf = (float*)alloc(8192 * 4);
  unsigned long long* Awords = (unsigned long long*)alloc((size_t)8192 * 128 * 8);
  unsigned long long* AT     = (unsigned long long*)alloc((size_t)8192 * 128 * 8);
  short* h0F  = (short*)alloc((size_t)8192 * 256 * 2);
  unsigned char* h0BF8 = (unsigned char*)alloc((size_t)8192 * 256);
  short* h1F  = (short*)alloc((size_t)8192 * 256 * 2);
  unsigned char* h1BF8 = (unsigned char*)alloc((size_t)8192 * 256);
  short* h2   = (short*)alloc((size_t)8192 * 256 * 2);
  short* aggF = (short*)alloc((size_t)8192 * 256 * 2);
  const size_t SLICE = (size_t)8192 * 256 * 2;
  int nsplit = (ws_size >= off + 8 * SLICE + 4096) ? 8
             : (ws_size >= off + 4 * SLICE + 4096) ? 4 : 2;
  short* partials = (short*)alloc((size_t)nsplit * SLICE);
  const int ksplit = 8192 / nsplit;

  hipMemsetAsync(hist1, 0, (NHC * 4096 + 8192) * 4, stream);
  prep_kernel<<<1280, 256, 0, stream>>>(x, w_in, h1_wl, h1_wr, h2_wl, h2_wr,
                                        xbF, xnF, w_inF, w1lF, w1rF, w2lF, w2rF);
  hist0_kernel<<<688, 256, 0, stream>>>(xnF, hist1);
  scan_kernel<4096, 0><<<1, 256, 0, stream>>>(hist1, sel);
  sim_kernel<1><<<NTRI / 4, 256, 0, stream>>>(xnF, hist2, sel, nullptr, nullptr);
  scan_kernel<8192, 1><<<1, 256, 0, stream>>>(hist2, sel);
  sim_kernel<2><<<NTRI / 4, 256, 0, stream>>>(xnF, nullptr, sel, Awords, AT);
  deg_kernel<<<2048, 256, 0, stream>>>(Awords, deg_inv);

  // h0 = relu(x @ w_in + b_in)  -> h0F (A-layout) + h0BF8 (fp8 B-layout)
  lin_kernel<false, true, false, true, true, false>
      <<<dim3(128, 4), 256, 0, stream>>>(xbF, w_inF, 128, nullptr, nullptr, 0,
                                         b_in, nullptr, h0F, h0BF8, nullptr);
  // h1 = relu(agg(h0)@h1_wl + h1_bl + h0@h1_wr)  -> h1F + h1BF8
  aggA_kernel<<<dim3(64, 2, nsplit), 256, 0, stream>>>(AT, h0BF8, partials, ksplit);
  combine_kernel<<<1024, 256, 0, stream>>>(partials, nsplit, deg_inv, aggF);
  lin_kernel<true, true, false, true, true, false>
      <<<dim3(128, 4), 256, 0, stream>>>(aggF, w1lF, 256, h0F, w1rF, 256,
                                         h1_bl, nullptr, h1F, h1BF8, nullptr);
  // h2 = relu(agg(h1)@h2_wl + h2_bl + h1@h2_wr + h0)  -> h2 row-major
  aggA_kernel<<<dim3(64, 2, nsplit), 256, 0, stream>>>(AT, h1BF8, partials, ksplit);
  combine_kernel<<<1024, 256, 0, stream>>>(partials, nsplit, deg_inv, aggF);
  lin_kernel<true, true, true, false, false, true>
      <<<dim3(128, 4), 256, 0, stream>>>(aggF, w2lF, 256, h1F, w2rF, 256,
                                         h2_bl, h0F, nullptr, nullptr, h2);
  // output block
  vec3_kernel<<<2048, 256, 0, stream>>>(h2, o1_wl, o1_wr, osc_w, osc_b, ubuf, vbuf, scbuf);
  aggv1_kernel<<<2048, 256, 0, stream>>>(Awords, ubuf, deg_inv, vbuf, o1_bl, o1buf);
  aggv2_kernel<<<2048, 256, 0, stream>>>(Awords, o1buf, deg_inv, o2_wl, o2_bl, o2_wr, scbuf, out);
}